// Round 1
// baseline (28820.398 us; speedup 1.0000x reference)
//
#include <hip/hip_runtime.h>
#include <cstdint>

// ---------------------------------------------------------------------------
// ForwardBackwardGNN — fp32 correctness-first implementation.
//
// Problem constants (match reference):
//   N=50000 nodes, E=400000 edges, L=16 tokens, V=64 vocab, EMB=32, H=128,
//   D=373, IN_IDX=161, OUT_IDX=320, SID=53, leaky slope 0.2.
//
// Algebraic pre-folds:
//   P[v][j]  = emb[v] . Wih_f[j,:] + bih_f[j] + bhh_f[j]   (emb row0 = 0)
//   FB[v][q] = b1[q] + sum_m hbwd(v)[m] * W1[128+m][q]     (reverse LSTM cell
//              with zero state depends only on token L-1 -> 64-entry table)
// so the per-edge work is only: 16 steps of h @ Whh_f^T (+P lookup), then
// feat = relu(h @ W1[:128] + FB[tok15]) ; ea = relu(feat.W2 + b2).
//
// Workspace requirement: ~252.3 MB (see layout in kernel_launch).
// ---------------------------------------------------------------------------

#define D_DIM   373
#define SID_N   53
#define IN_COL  161
#define OUT_COL 320

__device__ __forceinline__ float sig_f(float x)  { return 1.0f / (1.0f + __expf(-x)); }
__device__ __forceinline__ float tanh_f(float x) { return 2.0f / (1.0f + __expf(-2.0f * x)) - 1.0f; }

// ---------------- generic fill ----------------
__global__ void fill_u32_kernel(unsigned* __restrict__ p, unsigned v, size_t n) {
  size_t i = (size_t)blockIdx.x * blockDim.x + threadIdx.x;
  size_t stride = (size_t)gridDim.x * blockDim.x;
  for (; i < n; i += stride) p[i] = v;
}

// ---------------- precompute tables ----------------
// grid = 64 (one block per vocab id), block = 512 threads (one per gate j).
__global__ void precompute_kernel(
    const float* __restrict__ embed, const float* __restrict__ Wih_f,
    const float* __restrict__ Whh_f,
    const float* __restrict__ bih_f, const float* __restrict__ bhh_f,
    const float* __restrict__ Wih_r,
    const float* __restrict__ bih_r, const float* __restrict__ bhh_r,
    const float* __restrict__ W1, const float* __restrict__ b1,
    float* __restrict__ P, float* __restrict__ FB,
    float* __restrict__ WhhT, float* __restrict__ W1aT)
{
  __shared__ float gb[512];
  __shared__ float hb[128];
  int v = blockIdx.x;
  int j = threadIdx.x;

  // forward-input table (bias folded)
  float s = 0.0f;
  if (v != 0) {
    #pragma unroll
    for (int k = 0; k < 32; ++k) s += embed[v * 32 + k] * Wih_f[j * 32 + k];
  }
  P[v * 512 + j] = s + bih_f[j] + bhh_f[j];

  // reverse cell (zero state): gates
  float gr = bih_r[j] + bhh_r[j];
  if (v != 0) {
    #pragma unroll
    for (int k = 0; k < 32; ++k) gr += embed[v * 32 + k] * Wih_r[j * 32 + k];
  }
  gb[j] = gr;
  __syncthreads();
  if (j < 128) {
    // c = sig(i)*tanh(g)  (f-term vanishes, c0=0) ; h = sig(o)*tanh(c)
    float c = sig_f(gb[j]) * tanh_f(gb[256 + j]);
    hb[j] = sig_f(gb[384 + j]) * tanh_f(c);
  }
  __syncthreads();
  if (j < 32) {
    float s2 = b1[j];
    for (int m = 0; m < 128; ++m) s2 += hb[m] * W1[(128 + m) * 32 + j];
    FB[v * 32 + j] = s2;
  }
  if (v == 0) {
    // WhhT[k][j] = Whh_f[j][k]  (contiguous j-runs -> scalar dwordx loads)
    for (int k = 0; k < 128; ++k) WhhT[k * 512 + j] = Whh_f[j * 128 + k];
    if (j < 128) {
      for (int q = 0; q < 32; ++q) W1aT[q * 128 + j] = W1[j * 32 + q];
    }
  }
}

// ---------------- LSTM forward + MLP -> edge scalar ----------------
// block = 256 thr (4 waves); 64 edges/block, lane = edge.
// wave w owns hidden rows m in [32w, 32w+32): gates j = m,128+m,256+m,384+m.
__global__ __launch_bounds__(256, 2) void lstm_kernel(
    const int*   __restrict__ tokens,  // [E][16]
    const float* __restrict__ P,       // [64][512]
    const float* __restrict__ FB,      // [64][32]
    const float* __restrict__ WhhT,    // [128][512]
    const float* __restrict__ W1aT,    // [32][128]
    const float* __restrict__ W2,      // [32]
    const float* __restrict__ b2,      // [1]
    float* __restrict__ ea, int E)
{
  __shared__ float Hs[64][132];    // h, padded stride (16B-aligned rows)
  __shared__ float featS[64][33];
  int tid  = threadIdx.x;
  int lane = tid & 63;
  int wv   = __builtin_amdgcn_readfirstlane(tid >> 6);
  int w32  = wv * 32;
  long e   = (long)blockIdx.x * 64 + lane;
  long el  = (e < E) ? e : (long)E - 1;

  for (int i = tid; i < 64 * 132; i += 256) (&Hs[0][0])[i] = 0.0f;

  int tok[16];
  #pragma unroll
  for (int t = 0; t < 16; ++t) tok[t] = tokens[el * 16 + t];

  float c_[32];
  #pragma unroll
  for (int r = 0; r < 32; ++r) c_[r] = 0.0f;

  __syncthreads();

  #pragma unroll 1
  for (int t = 0; t < 16; ++t) {
    float ai[32], af[32], ag[32], ao[32];
    const float4* P4 = (const float4*)(P + (size_t)tok[t] * 512 + w32);
    #pragma unroll
    for (int r4 = 0; r4 < 8; ++r4) {
      float4 pi = P4[r4], pf = P4[32 + r4], pg = P4[64 + r4], po = P4[96 + r4];
      ai[r4*4+0]=pi.x; ai[r4*4+1]=pi.y; ai[r4*4+2]=pi.z; ai[r4*4+3]=pi.w;
      af[r4*4+0]=pf.x; af[r4*4+1]=pf.y; af[r4*4+2]=pf.z; af[r4*4+3]=pf.w;
      ag[r4*4+0]=pg.x; ag[r4*4+1]=pg.y; ag[r4*4+2]=pg.z; ag[r4*4+3]=pg.w;
      ao[r4*4+0]=po.x; ao[r4*4+1]=po.y; ao[r4*4+2]=po.z; ao[r4*4+3]=po.w;
    }
    #pragma unroll 1
    for (int kc = 0; kc < 16; ++kc) {
      const float4* hp = (const float4*)&Hs[lane][kc * 8];
      float4 h0 = hp[0], h1 = hp[1];
      float hm[8] = {h0.x, h0.y, h0.z, h0.w, h1.x, h1.y, h1.z, h1.w};
      const float* Wb = WhhT + (size_t)(kc * 8) * 512 + w32;
      #pragma unroll
      for (int kk = 0; kk < 8; ++kk) {
        const float* Wr = Wb + kk * 512;   // wave-uniform -> scalar loads
        float av = hm[kk];
        #pragma unroll
        for (int r = 0; r < 32; ++r) {
          ai[r] = fmaf(Wr[r],       av, ai[r]);
          af[r] = fmaf(Wr[128 + r], av, af[r]);
          ag[r] = fmaf(Wr[256 + r], av, ag[r]);
          ao[r] = fmaf(Wr[384 + r], av, ao[r]);
        }
      }
    }
    __syncthreads();   // all waves done READING Hs for this step
    float hn[32];
    #pragma unroll
    for (int r = 0; r < 32; ++r) {
      float iv = sig_f(ai[r]);
      float fv = sig_f(af[r]);
      float gv = tanh_f(ag[r]);
      float ov = sig_f(ao[r]);
      float cn = fv * c_[r] + iv * gv;
      c_[r] = cn;
      hn[r] = ov * tanh_f(cn);
    }
    float4* hw = (float4*)&Hs[lane][w32];
    #pragma unroll
    for (int r4 = 0; r4 < 8; ++r4)
      hw[r4] = make_float4(hn[r4*4], hn[r4*4+1], hn[r4*4+2], hn[r4*4+3]);
    __syncthreads();
  }

  // MLP tail: wave w computes feat[q] for q in [8w, 8w+8)
  int w8 = wv * 8;
  float fq[8];
  const float4* FB4 = (const float4*)(FB + (size_t)tok[15] * 32 + w8);
  float4 f0 = FB4[0], f1 = FB4[1];
  fq[0]=f0.x; fq[1]=f0.y; fq[2]=f0.z; fq[3]=f0.w;
  fq[4]=f1.x; fq[5]=f1.y; fq[6]=f1.z; fq[7]=f1.w;
  #pragma unroll 1
  for (int mc = 0; mc < 16; ++mc) {
    const float4* hp = (const float4*)&Hs[lane][mc * 8];
    float4 h0 = hp[0], h1 = hp[1];
    float hm[8] = {h0.x, h0.y, h0.z, h0.w, h1.x, h1.y, h1.z, h1.w};
    #pragma unroll
    for (int kk = 0; kk < 8; ++kk) {
      #pragma unroll
      for (int q = 0; q < 8; ++q)
        fq[q] = fmaf(W1aT[(w8 + q) * 128 + mc * 8 + kk], hm[kk], fq[q]);
    }
  }
  #pragma unroll
  for (int q = 0; q < 8; ++q)
    featS[lane][w8 + q] = fmaxf(fq[q], 0.0f);
  __syncthreads();
  if (wv == 0 && e < E) {
    float sv = b2[0];
    #pragma unroll
    for (int q = 0; q < 32; ++q) sv = fmaf(featS[lane][q], W2[q], sv);
    ea[e] = fmaxf(sv, 0.0f);
  }
}

// ---------------- argmax ids + scatter winner (last edge wins) ----------------
__global__ void argmax_winner_kernel(
    const float* __restrict__ x, const int* __restrict__ ei, int E,
    int* __restrict__ srcid, int* __restrict__ tgtid,
    int* __restrict__ win_in, int* __restrict__ win_out)
{
  int e = blockIdx.x * 256 + threadIdx.x;
  if (e >= E) return;
  int s = ei[e];
  int t = ei[E + e];
  const float* xs = x + (size_t)s * D_DIM;
  int sid = 0; float bv = xs[0];
  for (int k = 1; k < SID_N; ++k) { float v = xs[k]; if (v > bv) { bv = v; sid = k; } }
  const float* xt = x + (size_t)t * D_DIM;
  int tix = 0; bv = xt[0];
  for (int k = 1; k < SID_N; ++k) { float v = xt[k]; if (v > bv) { bv = v; tix = k; } }
  srcid[e] = sid;
  tgtid[e] = tix;
  atomicMax(&win_in[(size_t)t * SID_N + sid], e);
  atomicMax(&win_out[(size_t)s * SID_N + tix], e);
}

__global__ void scatter_resolve_kernel(
    const int* __restrict__ ei, const float* __restrict__ ea,
    const int* __restrict__ srcid, const int* __restrict__ tgtid,
    const int* __restrict__ win_in, const int* __restrict__ win_out,
    float* __restrict__ x_mod, int E)
{
  int e = blockIdx.x * 256 + threadIdx.x;
  if (e >= E) return;
  int s = ei[e];
  int t = ei[E + e];
  int sid = srcid[e], tix = tgtid[e];
  if (win_in[(size_t)t * SID_N + sid] == e)
    x_mod[(size_t)t * D_DIM + IN_COL + sid] = ea[e];
  if (win_out[(size_t)s * SID_N + tix] == e)
    x_mod[(size_t)s * D_DIM + OUT_COL + tix] = ea[e];
}

// ---------------- tiled fp32 GEMM: C[M][Nn] = A[M][K] @ B[K][Nn] + bias ----------------
__global__ __launch_bounds__(256) void gemm_bias_kernel(
    const float* __restrict__ A, const float* __restrict__ B,
    const float* __restrict__ bias, float* __restrict__ C,
    int M, int Nn, int K)
{
  __shared__ float As[16][64];
  __shared__ float Bs[16][64];
  int tid = threadIdx.x;
  int bm = blockIdx.x * 64;
  int bn = blockIdx.y * 64;
  int tx = tid & 15, ty = tid >> 4;
  float acc[4][4] = {};
  for (int k0 = 0; k0 < K; k0 += 16) {
    int am = tid >> 2, ak = (tid & 3) * 4;
    int gm = bm + am;
    #pragma unroll
    for (int c = 0; c < 4; ++c) {
      int gk = k0 + ak + c;
      As[ak + c][am] = (gm < M && gk < K) ? A[(size_t)gm * K + gk] : 0.0f;
    }
    int nn = tid & 63;
    int kr = tid >> 6;
    #pragma unroll
    for (int rr = 0; rr < 4; ++rr) {
      int gk = k0 + kr + rr * 4;
      Bs[kr + rr * 4][nn] = (gk < K && bn + nn < Nn) ? B[(size_t)gk * Nn + bn + nn] : 0.0f;
    }
    __syncthreads();
    #pragma unroll
    for (int kk = 0; kk < 16; ++kk) {
      float4 a4 = *(const float4*)&As[kk][ty * 4];
      float4 b4 = *(const float4*)&Bs[kk][tx * 4];
      float aa[4] = {a4.x, a4.y, a4.z, a4.w};
      float bb[4] = {b4.x, b4.y, b4.z, b4.w};
      #pragma unroll
      for (int i = 0; i < 4; ++i)
        #pragma unroll
        for (int j = 0; j < 4; ++j)
          acc[i][j] = fmaf(aa[i], bb[j], acc[i][j]);
    }
    __syncthreads();
  }
  #pragma unroll
  for (int i = 0; i < 4; ++i) {
    int m = bm + ty * 4 + i;
    if (m >= M) continue;
    #pragma unroll
    for (int j = 0; j < 4; ++j) {
      int n = bn + tx * 4 + j;
      if (n < Nn) C[(size_t)m * Nn + n] = acc[i][j] + bias[n];
    }
  }
}

// ---------------- GAT attention logits + segment max ----------------
// one wave per edge
__device__ __forceinline__ unsigned fmap_u(float f) {
  unsigned u = __float_as_uint(f);
  return (u & 0x80000000u) ? ~u : (u | 0x80000000u);
}
__device__ __forceinline__ float fumap(unsigned u) {
  return __uint_as_float((u & 0x80000000u) ? (u ^ 0x80000000u) : ~u);
}

__global__ __launch_bounds__(256) void edge_e_kernel(
    const float* __restrict__ xl, const float* __restrict__ xr,
    const float* __restrict__ att, const int* __restrict__ ei,
    float* __restrict__ e_buf, unsigned* __restrict__ emax_u, int E)
{
  int widx = (blockIdx.x * 256 + threadIdx.x) >> 6;
  int lane = threadIdx.x & 63;
  if (widx >= E) return;
  int s = ei[widx], t = ei[E + widx];
  const float* pl = xl + (size_t)s * D_DIM;
  const float* pr = xr + (size_t)t * D_DIM;
  float acc = 0.0f;
  for (int d = lane; d < D_DIM; d += 64) {
    float m = pl[d] + pr[d];
    m = (m > 0.0f) ? m : 0.2f * m;
    acc += m * att[d];
  }
  #pragma unroll
  for (int o = 32; o > 0; o >>= 1) acc += __shfl_down(acc, o);
  if (lane == 0) {
    e_buf[widx] = acc;
    atomicMax(&emax_u[t], fmap_u(acc));
  }
}

__global__ void softmax_denom_kernel(
    const int* __restrict__ ei, float* __restrict__ e_buf,
    const unsigned* __restrict__ emax_u, float* __restrict__ denom, int E)
{
  int e = blockIdx.x * 256 + threadIdx.x;
  if (e >= E) return;
  int t = ei[E + e];
  float mx = fumap(emax_u[t]);
  float ex = __expf(e_buf[e] - mx);
  e_buf[e] = ex;                    // overwrite logits with exp values
  atomicAdd(&denom[t], ex);
}

__global__ __launch_bounds__(256) void aggregate_kernel(
    const int* __restrict__ ei, const float* __restrict__ e_buf,
    const float* __restrict__ denom, const float* __restrict__ xl,
    float* __restrict__ agg, int E)
{
  int widx = (blockIdx.x * 256 + threadIdx.x) >> 6;
  int lane = threadIdx.x & 63;
  if (widx >= E) return;
  int s = ei[widx], t = ei[E + widx];
  float alpha = e_buf[widx] / (denom[t] + 1e-16f);
  const float* pl = xl + (size_t)s * D_DIM;
  float* pa = agg + (size_t)t * D_DIM;
  for (int d = lane; d < D_DIM; d += 64)
    atomicAdd(&pa[d], alpha * pl[d]);
}

__global__ void finalize_kernel(
    const float* __restrict__ agg, const float* __restrict__ x_mod,
    const float* __restrict__ bias, float* __restrict__ out, int N, int goff)
{
  int i = blockIdx.x * 256 + threadIdx.x;
  int total = N * D_DIM;
  if (i >= total) return;
  int n = i / D_DIM;
  int d = i - n * D_DIM;
  float v = agg[i] + bias[d] + x_mod[i];
  out[(size_t)n * (2 * D_DIM) + goff + d] = fmaxf(v, 0.0f);
}

// ---------------------------------------------------------------------------
extern "C" void kernel_launch(void* const* d_in, const int* in_sizes, int n_in,
                              void* d_out, int out_size, void* d_ws, size_t ws_size,
                              hipStream_t stream)
{
  const float* fx     = (const float*)d_in[0];
  const float* bx     = (const float*)d_in[1];
  const int*   fei    = (const int*)d_in[2];
  const int*   bei    = (const int*)d_in[3];
  const int*   ftk    = (const int*)d_in[4];
  const int*   btk    = (const int*)d_in[5];
  const float* embed  = (const float*)d_in[6];
  const float* Wih_f  = (const float*)d_in[7];
  const float* Whh_f  = (const float*)d_in[8];
  const float* bih_f  = (const float*)d_in[9];
  const float* bhh_f  = (const float*)d_in[10];
  const float* Wih_r  = (const float*)d_in[11];
  // d_in[12] = Whh_r : unused (reverse cell consumes zero state)
  const float* bih_r  = (const float*)d_in[13];
  const float* bhh_r  = (const float*)d_in[14];
  const float* W1     = (const float*)d_in[15];
  const float* b1     = (const float*)d_in[16];
  const float* W2     = (const float*)d_in[17];
  const float* b2     = (const float*)d_in[18];

  const float* Wl_g[2]   = {(const float*)d_in[19], (const float*)d_in[25]};
  const float* bl_g[2]   = {(const float*)d_in[20], (const float*)d_in[26]};
  const float* Wr_g[2]   = {(const float*)d_in[21], (const float*)d_in[27]};
  const float* br_g[2]   = {(const float*)d_in[22], (const float*)d_in[28]};
  const float* att_g[2]  = {(const float*)d_in[23], (const float*)d_in[29]};
  const float* bias_g[2] = {(const float*)d_in[24], (const float*)d_in[30]};
  const float* x_g[2]    = {fx, bx};
  const int*   ei_g[2]   = {fei, bei};
  const int*   tk_g[2]   = {ftk, btk};

  const int E = in_sizes[2] / 2;          // 400000
  const int N = in_sizes[0] / D_DIM;      // 50000

  // ---- workspace layout (floats) — total ~63.06M elems = ~252.3 MB ----
  float* ws = (float*)d_ws;
  size_t off = 0;
  float* P     = ws + off; off += 64 * 512;
  float* FB    = ws + off; off += 64 * 32;
  float* WhhT  = ws + off; off += 128 * 512;
  float* W1aT  = ws + off; off += 32 * 128;
  float* ea    = ws + off; off += (size_t)E;
  float* ebuf  = ws + off; off += (size_t)E;
  int*   srcid = (int*)(ws + off); off += (size_t)E;
  int*   tgtid = (int*)(ws + off); off += (size_t)E;
  unsigned* emaxu = (unsigned*)(ws + off); off += (size_t)N;
  float* denom = ws + off; off += (size_t)N;
  int* win_in  = (int*)(ws + off); off += (size_t)N * SID_N;
  int* win_out = (int*)(ws + off); off += (size_t)N * SID_N;
  float* xmod  = ws + off; off += (size_t)N * D_DIM;
  float* xl    = ws + off; off += (size_t)N * D_DIM;
  float* xr    = ws + off; off += (size_t)N * D_DIM;   // reused as agg
  (void)ws_size; (void)n_in; (void)out_size;

  float* out = (float*)d_out;

  precompute_kernel<<<64, 512, 0, stream>>>(
      embed, Wih_f, Whh_f, bih_f, bhh_f, Wih_r, bih_r, bhh_r, W1, b1,
      P, FB, WhhT, W1aT);

  const int gridL   = (E + 63) / 64;
  const int gridE   = (E + 255) / 256;
  const int gridEW  = (E + 3) / 4;               // wave-per-edge kernels
  const int gridFin = (N * D_DIM + 255) / 256;
  dim3 gridG((N + 63) / 64, (D_DIM + 63) / 64);

  for (int g = 0; g < 2; ++g) {
    const float* x  = x_g[g];
    const int*   ei = ei_g[g];

    // (1) edge scalar via LSTM
    lstm_kernel<<<gridL, 256, 0, stream>>>(tk_g[g], P, FB, WhhT, W1aT, W2, b2, ea, E);

    // (2) x_mod = copy(x), then last-edge-wins scatter writes
    hipMemcpyAsync(xmod, x, (size_t)N * D_DIM * sizeof(float),
                   hipMemcpyDeviceToDevice, stream);
    fill_u32_kernel<<<2048, 256, 0, stream>>>((unsigned*)win_in, 0xFFFFFFFFu,
                                              (size_t)2 * N * SID_N);
    argmax_winner_kernel<<<gridE, 256, 0, stream>>>(x, ei, E, srcid, tgtid,
                                                    win_in, win_out);
    scatter_resolve_kernel<<<gridE, 256, 0, stream>>>(ei, ea, srcid, tgtid,
                                                      win_in, win_out, xmod, E);

    // (3) xl = xmod @ Wl + bl ; xr = xmod @ Wr + br
    gemm_bias_kernel<<<gridG, 256, 0, stream>>>(xmod, Wl_g[g], bl_g[g], xl,
                                                N, D_DIM, D_DIM);
    gemm_bias_kernel<<<gridG, 256, 0, stream>>>(xmod, Wr_g[g], br_g[g], xr,
                                                N, D_DIM, D_DIM);

    // (4) attention logits + scatter softmax
    fill_u32_kernel<<<512, 256, 0, stream>>>((unsigned*)emaxu, 0u, (size_t)2 * N);
    edge_e_kernel<<<gridEW, 256, 0, stream>>>(xl, xr, att_g[g], ei, ebuf, emaxu, E);
    softmax_denom_kernel<<<gridE, 256, 0, stream>>>(ei, ebuf, emaxu, denom, E);

    // (5) aggregate (xr reused as agg, zeroed first)
    fill_u32_kernel<<<2048, 256, 0, stream>>>((unsigned*)xr, 0u, (size_t)N * D_DIM);
    aggregate_kernel<<<gridEW, 256, 0, stream>>>(ei, ebuf, denom, xl, xr, E);

    // (6) out[:, g*373 : g*373+373] = relu(agg + bias + x_mod)
    finalize_kernel<<<gridFin, 256, 0, stream>>>(xr, xmod, bias_g[g], out, N,
                                                 g * D_DIM);
  }
}

// Round 3
// 5929.364 us; speedup vs baseline: 4.8606x; 4.8606x over previous
//
#include <hip/hip_runtime.h>
#include <cstdint>

// ---------------------------------------------------------------------------
// ForwardBackwardGNN — R3: R2 (MFMA LSTM) + span-exact workspace fills.
//   R2 bug: fused fills assumed buffer contiguity, but 256B alloc padding
//   left the last 48 denom entries un-zeroed -> cross-call accumulation.
//   N=50000, E=400000, L=16, V=64, EMB=32, H=128, D=373, SID=53.
// ---------------------------------------------------------------------------

#define D_DIM   373
#define SID_N   53
#define IN_COL  161
#define OUT_COL 320
#define HS_STRIDE 136   // bf16 elems per Hs row

typedef short bf16x8 __attribute__((ext_vector_type(8)));
typedef float f32x4  __attribute__((ext_vector_type(4)));

__device__ __forceinline__ float fast_exp2(float x) {
#if __has_builtin(__builtin_amdgcn_exp2f)
  return __builtin_amdgcn_exp2f(x);
#else
  return exp2f(x);
#endif
}
__device__ __forceinline__ float fast_rcp(float x) {
#if __has_builtin(__builtin_amdgcn_rcpf)
  return __builtin_amdgcn_rcpf(x);
#else
  return 1.0f / x;
#endif
}
__device__ __forceinline__ float sigf(float x) {
  return fast_rcp(1.0f + fast_exp2(-1.4426950408889634f * x));
}
__device__ __forceinline__ float tanhf_(float x) {
  return 1.0f - 2.0f * fast_rcp(1.0f + fast_exp2(2.8853900817779268f * x));
}
__device__ __forceinline__ float sig_ref(float x)  { return 1.0f / (1.0f + __expf(-x)); }
__device__ __forceinline__ float tanh_ref(float x) { return 2.0f / (1.0f + __expf(-2.0f * x)) - 1.0f; }

__device__ __forceinline__ unsigned short f2bf(float f) {
  unsigned u = __float_as_uint(f);
  unsigned r = (u + 0x7fffu + ((u >> 16) & 1u)) >> 16;
  return (unsigned short)r;
}
__device__ __forceinline__ float bflo2f(unsigned u) { return __uint_as_float(u << 16); }
__device__ __forceinline__ float bfhi2f(unsigned u) { return __uint_as_float(u & 0xffff0000u); }

// ---------------- generic fill ----------------
__global__ void fill_u32_kernel(unsigned* __restrict__ p, unsigned v, size_t n) {
  size_t i = (size_t)blockIdx.x * blockDim.x + threadIdx.x;
  size_t stride = (size_t)gridDim.x * blockDim.x;
  for (; i < n; i += stride) p[i] = v;
}

// ---------------- precompute: Pg / FB / MFMA B-fragments ----------------
// grid = 64 (one block per vocab id), block = 512.
__global__ void precompute_kernel(
    const float* __restrict__ embed, const float* __restrict__ Wih_f,
    const float* __restrict__ Whh_f,
    const float* __restrict__ bih_f, const float* __restrict__ bhh_f,
    const float* __restrict__ Wih_r,
    const float* __restrict__ bih_r, const float* __restrict__ bhh_r,
    const float* __restrict__ W1, const float* __restrict__ b1,
    unsigned short* __restrict__ Pg, unsigned short* __restrict__ BfragW,
    unsigned short* __restrict__ Bfrag1, float* __restrict__ FB)
{
  __shared__ float ps[512];
  __shared__ float gb[512];
  __shared__ float hb[128];
  int v = blockIdx.x;
  int j = threadIdx.x;

  float s = 0.0f;
  if (v != 0) {
    #pragma unroll
    for (int k = 0; k < 32; ++k) s += embed[v * 32 + k] * Wih_f[j * 32 + k];
  }
  ps[j] = s + bih_f[j] + bhh_f[j];

  float gr = bih_r[j] + bhh_r[j];
  if (v != 0) {
    #pragma unroll
    for (int k = 0; k < 32; ++k) gr += embed[v * 32 + k] * Wih_r[j * 32 + k];
  }
  gb[j] = gr;
  __syncthreads();
  if (j < 128) {
    float c = sig_ref(gb[j]) * tanh_ref(gb[256 + j]);
    hb[j] = sig_ref(gb[384 + j]) * tanh_ref(c);
  }
  __syncthreads();

  // Pg[v][h][g] = bf16(P[v][g*128+h])
  { int h = j >> 2, g = j & 3;
    Pg[((size_t)v * 128 + h) * 4 + g] = f2bf(ps[g * 128 + h]); }

  if (j < 32) {
    float s2 = b1[j];
    for (int m = 0; m < 128; ++m) s2 += hb[m] * W1[(128 + m) * 32 + j];
    FB[v * 32 + j] = s2;
  }

  if (v == 0) {
    // BfragW flat = ((nt*4+ks)*64 + lane)*8 + e ;  B[k][n] = Whh_f[n][k]
    for (int f = j; f < 65536; f += 512) {
      int e = f & 7, l = (f >> 3) & 63, ks = (f >> 9) & 3, nt = f >> 11;
      int n = nt * 16 + (l & 15);
      int k = ks * 32 + (l >> 4) * 8 + e;
      BfragW[f] = f2bf(Whh_f[(size_t)n * 128 + k]);
    }
  }
  if (v == 1) {
    // Bfrag1 flat = ((n2*4+ks)*64 + lane)*8 + e ;  B[k][q] = W1[k][q] (k<128)
    for (int f = j; f < 4096; f += 512) {
      int e = f & 7, l = (f >> 3) & 63, ks = (f >> 9) & 3, n2 = f >> 11;
      int q = n2 * 16 + (l & 15);
      int k = ks * 32 + (l >> 4) * 8 + e;
      Bfrag1[f] = f2bf(W1[(size_t)k * 32 + q]);
    }
  }
}

// ---------------- MFMA LSTM: 16 edges/block, 4 waves, grid-stride ----------------
// Wave w owns gate columns {g*128 + w*32 + tt*16 + (lane&15)} for g=0..3, tt=0..1.
// C/D: col=lane&15, row=(lane>>4)*4+reg (m89). A/B packed with the same
// intra-group k-map (k = ks*32 + (lane>>4)*8 + e) so HW k-permutation cancels.
__global__ __launch_bounds__(256, 2) void lstm_mfma_kernel(
    const int*   __restrict__ tokens,   // [E][16]
    const unsigned short* __restrict__ Pg,      // [64][128][4] bf16
    const unsigned short* __restrict__ BfragW,  // [32][4][64][8] bf16
    const unsigned short* __restrict__ Bfrag1,  // [2][4][64][8] bf16
    const float* __restrict__ FB,       // [64][32]
    const float* __restrict__ W2,       // [32]
    const float* __restrict__ b2,
    float* __restrict__ ea, int E, int nTiles)
{
  __shared__ unsigned short Hs[2][16 * HS_STRIDE];
  __shared__ int toks[16][16];          // [t][m]

  int tid  = threadIdx.x;
  int lane = tid & 63;
  int wv   = tid >> 6;                  // 0..3
  int l15  = lane & 15;
  int lg   = lane >> 4;                 // 0..3

  // persistent Whh B-fragments: BW[g*2+tt][ks]
  bf16x8 BW[8][4];
  #pragma unroll
  for (int nt8 = 0; nt8 < 8; ++nt8) {
    int gate = nt8 >> 1, tt = nt8 & 1;
    int nt = gate * 8 + wv * 2 + tt;
    #pragma unroll
    for (int ks = 0; ks < 4; ++ks)
      BW[nt8][ks] = *(const bf16x8*)(BfragW + ((size_t)(nt * 4 + ks) * 64 + lane) * 8);
  }
  float w2a = W2[l15], w2b = W2[16 + l15];
  float b2v = b2[0];

  for (int tile = blockIdx.x; tile < nTiles; tile += gridDim.x) {
    int e0 = tile * 16;
    { // stage tokens: [t][m]
      int m = tid >> 4, t = tid & 15;
      int ee = e0 + m; if (ee >= E) ee = E - 1;
      toks[t][m] = tokens[(size_t)ee * 16 + t];
    }
    __syncthreads();

    float cst[2][4];
    // ---- step 0: gates = Pg only (h0 = c0 = 0)
    #pragma unroll
    for (int tt = 0; tt < 2; ++tt) {
      int hcol = wv * 32 + tt * 16 + l15;
      #pragma unroll
      for (int r = 0; r < 4; ++r) {
        int m = lg * 4 + r;
        int v = toks[0][m];
        uint2 pv = *(const uint2*)(Pg + ((size_t)v * 128 + hcol) * 4);
        float ii = sigf(bflo2f(pv.x));
        float gg = tanhf_(bflo2f(pv.y));
        float oo = sigf(bfhi2f(pv.y));
        float cn = ii * gg;
        cst[tt][r] = cn;
        Hs[0][m * HS_STRIDE + hcol] = f2bf(oo * tanhf_(cn));
      }
    }
    __syncthreads();

    int cur = 0;
    #pragma unroll 1
    for (int t = 1; t < 16; ++t) {
      // A-fragments of h(t-1): k = ks*32 + lg*8 + e (same map as BfragW)
      bf16x8 A[4];
      #pragma unroll
      for (int ks = 0; ks < 4; ++ks)
        A[ks] = *(const bf16x8*)(&Hs[cur][l15 * HS_STRIDE + ks * 32 + lg * 8]);

      // issue P gathers early
      int tokm[4];
      #pragma unroll
      for (int r = 0; r < 4; ++r) tokm[r] = toks[t][lg * 4 + r];
      uint2 pvv[2][4];
      #pragma unroll
      for (int tt = 0; tt < 2; ++tt) {
        int hcol = wv * 32 + tt * 16 + l15;
        #pragma unroll
        for (int r = 0; r < 4; ++r)
          pvv[tt][r] = *(const uint2*)(Pg + ((size_t)tokm[r] * 128 + hcol) * 4);
      }

      f32x4 acc[8];
      #pragma unroll
      for (int i = 0; i < 8; ++i) acc[i] = (f32x4){0.f, 0.f, 0.f, 0.f};
      #pragma unroll
      for (int ks = 0; ks < 4; ++ks)
        #pragma unroll
        for (int nt8 = 0; nt8 < 8; ++nt8)
          acc[nt8] = __builtin_amdgcn_mfma_f32_16x16x32_bf16(A[ks], BW[nt8][ks], acc[nt8], 0, 0, 0);

      #pragma unroll
      for (int tt = 0; tt < 2; ++tt) {
        int hcol = wv * 32 + tt * 16 + l15;
        #pragma unroll
        for (int r = 0; r < 4; ++r) {
          int m = lg * 4 + r;
          uint2 pv = pvv[tt][r];
          float ai = acc[0 + tt][r] + bflo2f(pv.x);
          float af = acc[2 + tt][r] + bfhi2f(pv.x);
          float ag = acc[4 + tt][r] + bflo2f(pv.y);
          float ao = acc[6 + tt][r] + bfhi2f(pv.y);
          float ii = sigf(ai), ff = sigf(af);
          float gg = tanhf_(ag), oo = sigf(ao);
          float cn = fmaf(ff, cst[tt][r], ii * gg);
          cst[tt][r] = cn;
          Hs[cur ^ 1][m * HS_STRIDE + hcol] = f2bf(oo * tanhf_(cn));
        }
      }
      cur ^= 1;
      __syncthreads();
    }

    // ---- tail: feat = relu(h15 @ W1[:128] + FB[tok15]) ; ea = relu(feat.W2 + b2)
    bf16x8 A[4];
    #pragma unroll
    for (int ks = 0; ks < 4; ++ks)
      A[ks] = *(const bf16x8*)(&Hs[cur][l15 * HS_STRIDE + ks * 32 + lg * 8]);
    f32x4 acc2[2];
    acc2[0] = (f32x4){0.f, 0.f, 0.f, 0.f};
    acc2[1] = (f32x4){0.f, 0.f, 0.f, 0.f};
    #pragma unroll
    for (int ks = 0; ks < 4; ++ks)
      #pragma unroll
      for (int n2 = 0; n2 < 2; ++n2)
        acc2[n2] = __builtin_amdgcn_mfma_f32_16x16x32_bf16(
            A[ks], *(const bf16x8*)(Bfrag1 + ((size_t)(n2 * 4 + ks) * 64 + lane) * 8),
            acc2[n2], 0, 0, 0);
    #pragma unroll
    for (int r = 0; r < 4; ++r) {
      int m = lg * 4 + r;
      int v15 = toks[15][m];
      float f0 = fmaxf(acc2[0][r] + FB[v15 * 32 + l15], 0.0f);
      float f1 = fmaxf(acc2[1][r] + FB[v15 * 32 + 16 + l15], 0.0f);
      float pr = fmaf(f0, w2a, f1 * w2b);
      pr += __shfl_xor(pr, 1);
      pr += __shfl_xor(pr, 2);
      pr += __shfl_xor(pr, 4);
      pr += __shfl_xor(pr, 8);
      int eidx = e0 + m;
      if (l15 == 0 && eidx < E) ea[eidx] = fmaxf(pr + b2v, 0.0f);
    }
    __syncthreads();   // before next tile reuses toks/Hs
  }
}

// ---------------- argmax ids + scatter winner (last edge wins) ----------------
__global__ void argmax_winner_kernel(
    const float* __restrict__ x, const int* __restrict__ ei, int E,
    int* __restrict__ srcid, int* __restrict__ tgtid,
    int* __restrict__ win_in, int* __restrict__ win_out)
{
  int e = blockIdx.x * 256 + threadIdx.x;
  if (e >= E) return;
  int s = ei[e];
  int t = ei[E + e];
  const float* xs = x + (size_t)s * D_DIM;
  int sid = 0; float bv = xs[0];
  for (int k = 1; k < SID_N; ++k) { float v = xs[k]; if (v > bv) { bv = v; sid = k; } }
  const float* xt = x + (size_t)t * D_DIM;
  int tix = 0; bv = xt[0];
  for (int k = 1; k < SID_N; ++k) { float v = xt[k]; if (v > bv) { bv = v; tix = k; } }
  srcid[e] = sid;
  tgtid[e] = tix;
  atomicMax(&win_in[(size_t)t * SID_N + sid], e);
  atomicMax(&win_out[(size_t)s * SID_N + tix], e);
}

__global__ void scatter_resolve_kernel(
    const int* __restrict__ ei, const float* __restrict__ ea,
    const int* __restrict__ srcid, const int* __restrict__ tgtid,
    const int* __restrict__ win_in, const int* __restrict__ win_out,
    float* __restrict__ x_mod, int E)
{
  int e = blockIdx.x * 256 + threadIdx.x;
  if (e >= E) return;
  int s = ei[e];
  int t = ei[E + e];
  int sid = srcid[e], tix = tgtid[e];
  if (win_in[(size_t)t * SID_N + sid] == e)
    x_mod[(size_t)t * D_DIM + IN_COL + sid] = ea[e];
  if (win_out[(size_t)s * SID_N + tix] == e)
    x_mod[(size_t)s * D_DIM + OUT_COL + tix] = ea[e];
}

// ---------------- tiled fp32 GEMM: C[M][Nn] = A[M][K] @ B[K][Nn] + bias ----------------
__global__ __launch_bounds__(256) void gemm_bias_kernel(
    const float* __restrict__ A, const float* __restrict__ B,
    const float* __restrict__ bias, float* __restrict__ C,
    int M, int Nn, int K)
{
  __shared__ float As[16][64];
  __shared__ float Bs[16][64];
  int tid = threadIdx.x;
  int bm = blockIdx.x * 64;
  int bn = blockIdx.y * 64;
  int tx = tid & 15, ty = tid >> 4;
  float acc[4][4] = {};
  for (int k0 = 0; k0 < K; k0 += 16) {
    int am = tid >> 2, ak = (tid & 3) * 4;
    int gm = bm + am;
    #pragma unroll
    for (int c = 0; c < 4; ++c) {
      int gk = k0 + ak + c;
      As[ak + c][am] = (gm < M && gk < K) ? A[(size_t)gm * K + gk] : 0.0f;
    }
    int nn = tid & 63;
    int kr = tid >> 6;
    #pragma unroll
    for (int rr = 0; rr < 4; ++rr) {
      int gk = k0 + kr + rr * 4;
      Bs[kr + rr * 4][nn] = (gk < K && bn + nn < Nn) ? B[(size_t)gk * Nn + bn + nn] : 0.0f;
    }
    __syncthreads();
    #pragma unroll
    for (int kk = 0; kk < 16; ++kk) {
      float4 a4 = *(const float4*)&As[kk][ty * 4];
      float4 b4 = *(const float4*)&Bs[kk][tx * 4];
      float aa[4] = {a4.x, a4.y, a4.z, a4.w};
      float bb[4] = {b4.x, b4.y, b4.z, b4.w};
      #pragma unroll
      for (int i = 0; i < 4; ++i)
        #pragma unroll
        for (int j = 0; j < 4; ++j)
          acc[i][j] = fmaf(aa[i], bb[j], acc[i][j]);
    }
    __syncthreads();
  }
  #pragma unroll
  for (int i = 0; i < 4; ++i) {
    int m = bm + ty * 4 + i;
    if (m >= M) continue;
    #pragma unroll
    for (int j = 0; j < 4; ++j) {
      int n = bn + tx * 4 + j;
      if (n < Nn) C[(size_t)m * Nn + n] = acc[i][j] + bias[n];
    }
  }
}

// ---------------- GAT attention ----------------
__device__ __forceinline__ unsigned fmap_u(float f) {
  unsigned u = __float_as_uint(f);
  return (u & 0x80000000u) ? ~u : (u | 0x80000000u);
}
__device__ __forceinline__ float fumap(unsigned u) {
  return __uint_as_float((u & 0x80000000u) ? (u ^ 0x80000000u) : ~u);
}

__global__ __launch_bounds__(256) void edge_e_kernel(
    const float* __restrict__ xl, const float* __restrict__ xr,
    const float* __restrict__ att, const int* __restrict__ ei,
    float* __restrict__ e_buf, unsigned* __restrict__ emax_u, int E)
{
  int widx = (blockIdx.x * 256 + threadIdx.x) >> 6;
  int lane = threadIdx.x & 63;
  if (widx >= E) return;
  int s = ei[widx], t = ei[E + widx];
  const float* pl = xl + (size_t)s * D_DIM;
  const float* pr = xr + (size_t)t * D_DIM;
  float acc = 0.0f;
  for (int d = lane; d < D_DIM; d += 64) {
    float m = pl[d] + pr[d];
    m = (m > 0.0f) ? m : 0.2f * m;
    acc += m * att[d];
  }
  #pragma unroll
  for (int o = 32; o > 0; o >>= 1) acc += __shfl_down(acc, o);
  if (lane == 0) {
    e_buf[widx] = acc;
    atomicMax(&emax_u[t], fmap_u(acc));
  }
}

__global__ void softmax_denom_kernel(
    const int* __restrict__ ei, float* __restrict__ e_buf,
    const unsigned* __restrict__ emax_u, float* __restrict__ denom, int E)
{
  int e = blockIdx.x * 256 + threadIdx.x;
  if (e >= E) return;
  int t = ei[E + e];
  float mx = fumap(emax_u[t]);
  float ex = __expf(e_buf[e] - mx);
  e_buf[e] = ex;
  atomicAdd(&denom[t], ex);
}

__global__ __launch_bounds__(256) void aggregate_kernel(
    const int* __restrict__ ei, const float* __restrict__ e_buf,
    const float* __restrict__ denom, const float* __restrict__ xl,
    float* __restrict__ agg, int E)
{
  int widx = (blockIdx.x * 256 + threadIdx.x) >> 6;
  int lane = threadIdx.x & 63;
  if (widx >= E) return;
  int s = ei[widx], t = ei[E + widx];
  float alpha = e_buf[widx] / (denom[t] + 1e-16f);
  const float* pl = xl + (size_t)s * D_DIM;
  float* pa = agg + (size_t)t * D_DIM;
  for (int d = lane; d < D_DIM; d += 64)
    atomicAdd(&pa[d], alpha * pl[d]);
}

__global__ void finalize_kernel(
    const float* __restrict__ agg, const float* __restrict__ x_mod,
    const float* __restrict__ bias, float* __restrict__ out, int N, int goff)
{
  int i = blockIdx.x * 256 + threadIdx.x;
  int total = N * D_DIM;
  if (i >= total) return;
  int n = i / D_DIM;
  int d = i - n * D_DIM;
  float v = agg[i] + bias[d] + x_mod[i];
  out[(size_t)n * (2 * D_DIM) + goff + d] = fmaxf(v, 0.0f);
}

// ---------------------------------------------------------------------------
extern "C" void kernel_launch(void* const* d_in, const int* in_sizes, int n_in,
                              void* d_out, int out_size, void* d_ws, size_t ws_size,
                              hipStream_t stream)
{
  const float* fx     = (const float*)d_in[0];
  const float* bx     = (const float*)d_in[1];
  const int*   fei    = (const int*)d_in[2];
  const int*   bei    = (const int*)d_in[3];
  const int*   ftk    = (const int*)d_in[4];
  const int*   btk    = (const int*)d_in[5];
  const float* embed  = (const float*)d_in[6];
  const float* Wih_f  = (const float*)d_in[7];
  const float* Whh_f  = (const float*)d_in[8];
  const float* bih_f  = (const float*)d_in[9];
  const float* bhh_f  = (const float*)d_in[10];
  const float* Wih_r  = (const float*)d_in[11];
  // d_in[12] = Whh_r : unused (reverse cell consumes zero state)
  const float* bih_r  = (const float*)d_in[13];
  const float* bhh_r  = (const float*)d_in[14];
  const float* W1     = (const float*)d_in[15];
  const float* b1     = (const float*)d_in[16];
  const float* W2     = (const float*)d_in[17];
  const float* b2     = (const float*)d_in[18];

  const float* Wl_g[2]   = {(const float*)d_in[19], (const float*)d_in[25]};
  const float* bl_g[2]   = {(const float*)d_in[20], (const float*)d_in[26]};
  const float* Wr_g[2]   = {(const float*)d_in[21], (const float*)d_in[27]};
  const float* br_g[2]   = {(const float*)d_in[22], (const float*)d_in[28]};
  const float* att_g[2]  = {(const float*)d_in[23], (const float*)d_in[29]};
  const float* bias_g[2] = {(const float*)d_in[24], (const float*)d_in[30]};
  const float* x_g[2]    = {fx, bx};
  const int*   ei_g[2]   = {fei, bei};
  const int*   tk_g[2]   = {ftk, btk};

  const int E = in_sizes[2] / 2;          // 400000
  const int N = in_sizes[0] / D_DIM;      // 50000

  // ---- workspace layout (byte-based, 256B aligned chunks) ----
  char* wsb = (char*)d_ws;
  size_t off = 0;
  auto alloc = [&](size_t bytes) -> void* {
    void* p = wsb + off; off += (bytes + 255) & ~(size_t)255; return p;
  };
  unsigned short* Pg     = (unsigned short*)alloc((size_t)64 * 128 * 4 * 2);
  unsigned short* BfragW = (unsigned short*)alloc((size_t)65536 * 2);
  unsigned short* Bfrag1 = (unsigned short*)alloc((size_t)4096 * 2);
  float* FB    = (float*)alloc((size_t)64 * 32 * 4);
  float* ea    = (float*)alloc((size_t)E * 4);
  float* ebuf  = (float*)alloc((size_t)E * 4);
  int*   srcid = (int*)alloc((size_t)E * 4);
  int*   tgtid = (int*)alloc((size_t)E * 4);
  unsigned* emaxu = (unsigned*)alloc((size_t)N * 4);
  float* denom = (float*)alloc((size_t)N * 4);
  int* win_in  = (int*)alloc((size_t)N * SID_N * 4);
  int* win_out = (int*)alloc((size_t)N * SID_N * 4);
  float* xmod  = (float*)alloc((size_t)N * D_DIM * 4);
  float* xl    = (float*)alloc((size_t)N * D_DIM * 4);
  float* xr    = (float*)alloc((size_t)N * D_DIM * 4);   // reused as agg
  (void)ws_size; (void)n_in; (void)out_size;

  // span-exact fill counts (include alignment padding between buffers):
  const size_t emax_denom_u32 = (size_t)((char*)denom - (char*)emaxu) / 4 + N;
  const size_t win_u32        = (size_t)((char*)win_out - (char*)win_in) / 4
                                + (size_t)N * SID_N;

  float* out = (float*)d_out;

  precompute_kernel<<<64, 512, 0, stream>>>(
      embed, Wih_f, Whh_f, bih_f, bhh_f, Wih_r, bih_r, bhh_r, W1, b1,
      Pg, BfragW, Bfrag1, FB);

  const int nTiles  = (E + 15) / 16;
  const int gridL   = nTiles < 2048 ? nTiles : 2048;
  const int gridE   = (E + 255) / 256;
  const int gridEW  = (E + 3) / 4;
  const int gridFin = (N * D_DIM + 255) / 256;
  dim3 gridG((N + 63) / 64, (D_DIM + 63) / 64);

  for (int g = 0; g < 2; ++g) {
    const float* x  = x_g[g];
    const int*   ei = ei_g[g];

    // (1) edge scalar via MFMA LSTM
    lstm_mfma_kernel<<<gridL, 256, 0, stream>>>(tk_g[g], Pg, BfragW, Bfrag1,
                                                FB, W2, b2, ea, E, nTiles);

    // (2) x_mod = copy(x), then last-edge-wins scatter writes
    hipMemcpyAsync(xmod, x, (size_t)N * D_DIM * sizeof(float),
                   hipMemcpyDeviceToDevice, stream);
    fill_u32_kernel<<<2048, 256, 0, stream>>>((unsigned*)win_in, 0xFFFFFFFFu,
                                              win_u32);
    argmax_winner_kernel<<<gridE, 256, 0, stream>>>(x, ei, E, srcid, tgtid,
                                                    win_in, win_out);
    scatter_resolve_kernel<<<gridE, 256, 0, stream>>>(ei, ea, srcid, tgtid,
                                                      win_in, win_out, xmod, E);

    // (3) xl = xmod @ Wl + bl ; xr = xmod @ Wr + br
    gemm_bias_kernel<<<gridG, 256, 0, stream>>>(xmod, Wl_g[g], bl_g[g], xl,
                                                N, D_DIM, D_DIM);
    gemm_bias_kernel<<<gridG, 256, 0, stream>>>(xmod, Wr_g[g], br_g[g], xr,
                                                N, D_DIM, D_DIM);

    // (4) attention logits + scatter softmax (emaxu+denom zeroed span-exactly)
    fill_u32_kernel<<<512, 256, 0, stream>>>((unsigned*)emaxu, 0u,
                                             emax_denom_u32);
    edge_e_kernel<<<gridEW, 256, 0, stream>>>(xl, xr, att_g[g], ei, ebuf, emaxu, E);
    softmax_denom_kernel<<<gridE, 256, 0, stream>>>(ei, ebuf, emaxu, denom, E);

    // (5) aggregate (xr reused as agg, zeroed first)
    fill_u32_kernel<<<2048, 256, 0, stream>>>((unsigned*)xr, 0u, (size_t)N * D_DIM);
    aggregate_kernel<<<gridEW, 256, 0, stream>>>(ei, ebuf, denom, xl, xr, E);

    // (6) out[:, g*373 : +373] = relu(agg + bias + x_mod)
    finalize_kernel<<<gridFin, 256, 0, stream>>>(xr, xmod, bias_g[g], out, N,
                                                 g * D_DIM);
  }
}

// Round 4
// 4901.124 us; speedup vs baseline: 5.8804x; 1.2098x over previous
//
#include <hip/hip_runtime.h>
#include <cstdint>

// ---------------------------------------------------------------------------
// ForwardBackwardGNN — R4.
//   LSTM: 8-wave/512-thr blocks, persistent per-wave B-frags (64 VGPR),
//         gate scales folded into weights/P, P as MFMA C-in.
//   GAT GEMMs: bf16 MFMA, fused xl||xr (768 packed cols).
//   N=50000, E=400000, L=16, V=64, EMB=32, H=128, D=373, SID=53.
// ---------------------------------------------------------------------------

#define D_DIM   373
#define SID_N   53
#define IN_COL  161
#define OUT_COL 320
#define HS_STRIDE 136   // bf16 elems per Hs row

typedef short bf16x8 __attribute__((ext_vector_type(8)));
typedef float f32x4  __attribute__((ext_vector_type(4)));

#define LOG2E_F 1.4426950408889634f
#define TWO_LOG2E_F 2.8853900817779268f

__device__ __forceinline__ float fast_exp2(float x) {
#if __has_builtin(__builtin_amdgcn_exp2f)
  return __builtin_amdgcn_exp2f(x);
#else
  return exp2f(x);
#endif
}
__device__ __forceinline__ float fast_rcp(float x) {
#if __has_builtin(__builtin_amdgcn_rcpf)
  return __builtin_amdgcn_rcpf(x);
#else
  return 1.0f / x;
#endif
}
// pre-scaled forms: input already multiplied by -log2e (sig) / +2log2e (tanh)
__device__ __forceinline__ float sig_pre(float y)  { return fast_rcp(1.0f + fast_exp2(y)); }
__device__ __forceinline__ float tanh_pre(float y) { return 1.0f - 2.0f * fast_rcp(1.0f + fast_exp2(y)); }
__device__ __forceinline__ float tanh_pl(float x)  { return tanh_pre(TWO_LOG2E_F * x); }

__device__ __forceinline__ float sig_ref(float x)  { return 1.0f / (1.0f + __expf(-x)); }
__device__ __forceinline__ float tanh_ref(float x) { return 2.0f / (1.0f + __expf(-2.0f * x)) - 1.0f; }

__device__ __forceinline__ unsigned short f2bf(float f) {
  unsigned u = __float_as_uint(f);
  unsigned r = (u + 0x7fffu + ((u >> 16) & 1u)) >> 16;
  return (unsigned short)r;
}
__device__ __forceinline__ float bflo2f(unsigned u) { return __uint_as_float(u << 16); }
__device__ __forceinline__ float bfhi2f(unsigned u) { return __uint_as_float(u & 0xffff0000u); }

// ---------------- generic fill ----------------
__global__ void fill_u32_kernel(unsigned* __restrict__ p, unsigned v, size_t n) {
  size_t i = (size_t)blockIdx.x * blockDim.x + threadIdx.x;
  size_t stride = (size_t)gridDim.x * blockDim.x;
  for (; i < n; i += stride) p[i] = v;
}

// ---------------- precompute: Pg / FB / MFMA B-fragments ----------------
// grid = 64 (one block per vocab id), block = 512.
// Pg and BfragW carry the folded gate scales: i,f,o -> -log2e ; g -> +2log2e.
__global__ void precompute_kernel(
    const float* __restrict__ embed, const float* __restrict__ Wih_f,
    const float* __restrict__ Whh_f,
    const float* __restrict__ bih_f, const float* __restrict__ bhh_f,
    const float* __restrict__ Wih_r,
    const float* __restrict__ bih_r, const float* __restrict__ bhh_r,
    const float* __restrict__ W1, const float* __restrict__ b1,
    unsigned short* __restrict__ Pg, unsigned short* __restrict__ BfragW,
    unsigned short* __restrict__ Bfrag1, float* __restrict__ FB)
{
  __shared__ float ps[512];
  __shared__ float gb[512];
  __shared__ float hb[128];
  int v = blockIdx.x;
  int j = threadIdx.x;

  float s = 0.0f;
  if (v != 0) {
    #pragma unroll
    for (int k = 0; k < 32; ++k) s += embed[v * 32 + k] * Wih_f[j * 32 + k];
  }
  ps[j] = s + bih_f[j] + bhh_f[j];

  float gr = bih_r[j] + bhh_r[j];
  if (v != 0) {
    #pragma unroll
    for (int k = 0; k < 32; ++k) gr += embed[v * 32 + k] * Wih_r[j * 32 + k];
  }
  gb[j] = gr;
  __syncthreads();
  if (j < 128) {
    float c = sig_ref(gb[j]) * tanh_ref(gb[256 + j]);
    hb[j] = sig_ref(gb[384 + j]) * tanh_ref(c);
  }
  __syncthreads();

  // Pg[v][h][g] = bf16(scale(g) * P[v][g*128+h])
  { int h = j >> 2, g = j & 3;
    float sc = (g == 2) ? TWO_LOG2E_F : -LOG2E_F;
    Pg[((size_t)v * 128 + h) * 4 + g] = f2bf(ps[g * 128 + h] * sc); }

  if (j < 32) {
    float s2 = b1[j];
    for (int m = 0; m < 128; ++m) s2 += hb[m] * W1[(128 + m) * 32 + j];
    FB[v * 32 + j] = s2;
  }

  if (v == 0) {
    // BfragW flat = ((nt*4+ks)*64 + lane)*8 + e ; B[k][n] = scale * Whh_f[n][k]
    for (int f = j; f < 65536; f += 512) {
      int e = f & 7, l = (f >> 3) & 63, ks = (f >> 9) & 3, nt = f >> 11;
      int n = nt * 16 + (l & 15);
      int k = ks * 32 + (l >> 4) * 8 + e;
      float sc = ((nt >> 3) == 2) ? TWO_LOG2E_F : -LOG2E_F;
      BfragW[f] = f2bf(Whh_f[(size_t)n * 128 + k] * sc);
    }
  }
  if (v == 1) {
    // Bfrag1 flat = ((n2*4+ks)*64 + lane)*8 + e ; B[k][q] = W1[k][q] (k<128)
    for (int f = j; f < 4096; f += 512) {
      int e = f & 7, l = (f >> 3) & 63, ks = (f >> 9) & 3, n2 = f >> 11;
      int q = n2 * 16 + (l & 15);
      int k = ks * 32 + (l >> 4) * 8 + e;
      Bfrag1[f] = f2bf(W1[(size_t)k * 32 + q]);
    }
  }
}

// ---------------- MFMA LSTM: 16 edges/block, 8 waves of 512, grid-stride ----
// Wave wv2 owns hidden cols [wv2*16, +16) x 4 gates (nt = gate*8 + wv2).
// C/D: col=lane&15, row=(lane>>4)*4+reg. A/B share k-map k=ks*32+(lane>>4)*8+e.
// P enters as the MFMA C-in (pre-scaled per gate).
__global__ __launch_bounds__(512, 4) void lstm_mfma_kernel(
    const int*   __restrict__ tokens,   // [E][16]
    const unsigned short* __restrict__ Pg,      // [64][128][4] bf16 (scaled)
    const unsigned short* __restrict__ BfragW,  // [32][4][64][8] bf16 (scaled)
    const unsigned short* __restrict__ Bfrag1,  // [2][4][64][8] bf16
    const float* __restrict__ FB,       // [64][32]
    const float* __restrict__ W2,       // [32]
    const float* __restrict__ b2,
    float* __restrict__ ea, int E, int nTiles)
{
  __shared__ unsigned short Hs[2][16 * HS_STRIDE];
  __shared__ int toks[16][16];          // [t][m]

  int tid  = threadIdx.x;
  int lane = tid & 63;
  int wv2  = tid >> 6;                  // 0..7
  int l15  = lane & 15;
  int lg   = lane >> 4;                 // 0..3
  int hcol = wv2 * 16 + l15;            // this lane's hidden column

  // persistent per-wave B-fragments: 16 frags = 64 VGPR
  bf16x8 BW[4][4];
  #pragma unroll
  for (int gate = 0; gate < 4; ++gate)
    #pragma unroll
    for (int ks = 0; ks < 4; ++ks)
      BW[gate][ks] = *(const bf16x8*)(BfragW +
          ((size_t)((gate * 8 + wv2) * 4 + ks) * 64 + lane) * 8);
  float w2a = W2[l15], w2b = W2[16 + l15];
  float b2v = b2[0];

  for (int tile = blockIdx.x; tile < nTiles; tile += gridDim.x) {
    int e0 = tile * 16;
    if (tid < 256) {                    // stage tokens [t][m]
      int m = tid >> 4, t = tid & 15;
      int ee = e0 + m; if (ee >= E) ee = E - 1;
      toks[t][m] = tokens[(size_t)ee * 16 + t];
    }
    __syncthreads();

    float cst[4];
    // ---- step 0: gates = P only (h0 = c0 = 0); f-gate term vanishes
    #pragma unroll
    for (int r = 0; r < 4; ++r) {
      int m = lg * 4 + r;
      uint2 pv = *(const uint2*)(Pg + ((size_t)toks[0][m] * 128 + hcol) * 4);
      float ii = sig_pre(bflo2f(pv.x));
      float gg = tanh_pre(bflo2f(pv.y));
      float oo = sig_pre(bfhi2f(pv.y));
      float cn = ii * gg;
      cst[r] = cn;
      Hs[0][m * HS_STRIDE + hcol] = f2bf(oo * tanh_pl(cn));
    }
    __syncthreads();

    int cur = 0;
    #pragma unroll 1
    for (int t = 1; t < 16; ++t) {
      // P gathers -> MFMA C-init (acc[gate][r], C/D row = lg*4+r)
      f32x4 acc[4];
      #pragma unroll
      for (int r = 0; r < 4; ++r) {
        uint2 pv = *(const uint2*)(Pg +
            ((size_t)toks[t][lg * 4 + r] * 128 + hcol) * 4);
        acc[0][r] = bflo2f(pv.x);   // i
        acc[1][r] = bfhi2f(pv.x);   // f
        acc[2][r] = bflo2f(pv.y);   // g
        acc[3][r] = bfhi2f(pv.y);   // o
      }
      #pragma unroll
      for (int ks = 0; ks < 4; ++ks) {
        bf16x8 A = *(const bf16x8*)(&Hs[cur][l15 * HS_STRIDE + ks * 32 + lg * 8]);
        #pragma unroll
        for (int gate = 0; gate < 4; ++gate)
          acc[gate] = __builtin_amdgcn_mfma_f32_16x16x32_bf16(
              A, BW[gate][ks], acc[gate], 0, 0, 0);
      }
      #pragma unroll
      for (int r = 0; r < 4; ++r) {
        int m = lg * 4 + r;
        float ii = sig_pre(acc[0][r]);
        float ff = sig_pre(acc[1][r]);
        float gg = tanh_pre(acc[2][r]);
        float oo = sig_pre(acc[3][r]);
        float cn = fmaf(ff, cst[r], ii * gg);
        cst[r] = cn;
        Hs[cur ^ 1][m * HS_STRIDE + hcol] = f2bf(oo * tanh_pl(cn));
      }
      cur ^= 1;
      __syncthreads();
    }

    // ---- tail (wave 0 only): feat = relu(h15 @ W1[:128] + FB[tok15]);
    //      ea = relu(feat . W2 + b2)
    if (wv2 == 0) {
      f32x4 acc2[2];
      acc2[0] = (f32x4){0.f, 0.f, 0.f, 0.f};
      acc2[1] = (f32x4){0.f, 0.f, 0.f, 0.f};
      #pragma unroll
      for (int ks = 0; ks < 4; ++ks) {
        bf16x8 A = *(const bf16x8*)(&Hs[cur][l15 * HS_STRIDE + ks * 32 + lg * 8]);
        #pragma unroll
        for (int n2 = 0; n2 < 2; ++n2)
          acc2[n2] = __builtin_amdgcn_mfma_f32_16x16x32_bf16(
              A, *(const bf16x8*)(Bfrag1 + ((size_t)(n2 * 4 + ks) * 64 + lane) * 8),
              acc2[n2], 0, 0, 0);
      }
      #pragma unroll
      for (int r = 0; r < 4; ++r) {
        int m = lg * 4 + r;
        int v15 = toks[15][m];
        float f0 = fmaxf(acc2[0][r] + FB[v15 * 32 + l15], 0.0f);
        float f1 = fmaxf(acc2[1][r] + FB[v15 * 32 + 16 + l15], 0.0f);
        float pr = fmaf(f0, w2a, f1 * w2b);
        pr += __shfl_xor(pr, 1);
        pr += __shfl_xor(pr, 2);
        pr += __shfl_xor(pr, 4);
        pr += __shfl_xor(pr, 8);
        int eidx = e0 + m;
        if (l15 == 0 && eidx < E) ea[eidx] = fmaxf(pr + b2v, 0.0f);
      }
    }
    __syncthreads();   // before next tile reuses toks/Hs
  }
}

// ---------------- argmax ids + scatter winner (last edge wins) ----------------
__global__ void argmax_winner_kernel(
    const float* __restrict__ x, const int* __restrict__ ei, int E,
    int* __restrict__ srcid, int* __restrict__ tgtid,
    int* __restrict__ win_in, int* __restrict__ win_out)
{
  int e = blockIdx.x * 256 + threadIdx.x;
  if (e >= E) return;
  int s = ei[e];
  int t = ei[E + e];
  const float* xs = x + (size_t)s * D_DIM;
  int sid = 0; float bv = xs[0];
  for (int k = 1; k < SID_N; ++k) { float v = xs[k]; if (v > bv) { bv = v; sid = k; } }
  const float* xt = x + (size_t)t * D_DIM;
  int tix = 0; bv = xt[0];
  for (int k = 1; k < SID_N; ++k) { float v = xt[k]; if (v > bv) { bv = v; tix = k; } }
  srcid[e] = sid;
  tgtid[e] = tix;
  atomicMax(&win_in[(size_t)t * SID_N + sid], e);
  atomicMax(&win_out[(size_t)s * SID_N + tix], e);
}

__global__ void scatter_resolve_kernel(
    const int* __restrict__ ei, const float* __restrict__ ea,
    const int* __restrict__ srcid, const int* __restrict__ tgtid,
    const int* __restrict__ win_in, const int* __restrict__ win_out,
    float* __restrict__ x_mod, int E)
{
  int e = blockIdx.x * 256 + threadIdx.x;
  if (e >= E) return;
  int s = ei[e];
  int t = ei[E + e];
  int sid = srcid[e], tix = tgtid[e];
  if (win_in[(size_t)t * SID_N + sid] == e)
    x_mod[(size_t)t * D_DIM + IN_COL + sid] = ea[e];
  if (win_out[(size_t)s * SID_N + tix] == e)
    x_mod[(size_t)s * D_DIM + OUT_COL + tix] = ea[e];
}

// ---------------- pack Wl||Wr into MFMA B-fragment order ----------------
// Wfrag flat = ((nt*12+ks)*64 + lane)*8 + e ; 48 nt (768 cols: xl 0-372 pad,
// xr at 384+), 12 ks (K=384, k<373 valid).
__global__ void pack_w_kernel(const float* __restrict__ Wl,
                              const float* __restrict__ Wr,
                              unsigned short* __restrict__ Wfrag)
{
  int f = blockIdx.x * 256 + threadIdx.x;
  if (f >= 48 * 12 * 64 * 8) return;
  int e = f & 7, l = (f >> 3) & 63;
  int rest = f >> 9;
  int ks = rest % 12, nt = rest / 12;
  int nl = nt * 16 + (l & 15);
  int k  = ks * 32 + (l >> 4) * 8 + e;
  float val = 0.0f;
  if (k < D_DIM) {
    if (nl < D_DIM)                      val = Wl[(size_t)k * D_DIM + nl];
    else if (nl >= 384 && nl < 384 + D_DIM) val = Wr[(size_t)k * D_DIM + (nl - 384)];
  }
  Wfrag[f] = f2bf(val);
}

// ---------------- fused bf16 MFMA GEMM: [xl||xr] = xmod @ [Wl||Wr] + bias ----
// grid (ceil(N/64), 12), block 256 (4 waves). Wave wv owns n-tile nt0+wv.
__global__ __launch_bounds__(256, 2) void gemm_mfma_kernel(
    const float* __restrict__ A,               // xmod [N][373] fp32
    const unsigned short* __restrict__ Wfrag,  // [48][12][64][8] bf16
    const float* __restrict__ bl, const float* __restrict__ br,
    float* __restrict__ xl, float* __restrict__ xr, int N)
{
  __shared__ unsigned short As[64][40];   // 64 rows x 32 cols bf16, stride 40
  int tid  = threadIdx.x;
  int lane = tid & 63;
  int wv   = tid >> 6;
  int l15  = lane & 15, lg = lane >> 4;
  int m0   = blockIdx.x * 64;
  int nt   = blockIdx.y * 4 + wv;

  f32x4 acc[4];
  #pragma unroll
  for (int i = 0; i < 4; ++i) acc[i] = (f32x4){0.f, 0.f, 0.f, 0.f};

  int srow = tid >> 2, seg = tid & 3;
  int gr = m0 + srow; if (gr >= N) gr = N - 1;
  const float* arow = A + (size_t)gr * D_DIM;

  for (int ks = 0; ks < 12; ++ks) {
    int c0 = ks * 32 + seg * 8;
    float v[8];
    #pragma unroll
    for (int j = 0; j < 8; ++j) v[j] = (c0 + j < D_DIM) ? arow[c0 + j] : 0.0f;
    unsigned pk0, pk1, pk2, pk3;
    asm("v_cvt_pk_bf16_f32 %0, %1, %2" : "=v"(pk0) : "v"(v[0]), "v"(v[1]));
    asm("v_cvt_pk_bf16_f32 %0, %1, %2" : "=v"(pk1) : "v"(v[2]), "v"(v[3]));
    asm("v_cvt_pk_bf16_f32 %0, %1, %2" : "=v"(pk2) : "v"(v[4]), "v"(v[5]));
    asm("v_cvt_pk_bf16_f32 %0, %1, %2" : "=v"(pk3) : "v"(v[6]), "v"(v[7]));
    __syncthreads();                       // prev iter's reads done
    *(uint4*)(&As[srow][seg * 8]) = make_uint4(pk0, pk1, pk2, pk3);
    __syncthreads();

    bf16x8 Bf = *(const bf16x8*)(Wfrag + ((size_t)(nt * 12 + ks) * 64 + lane) * 8);
    #pragma unroll
    for (int msub = 0; msub < 4; ++msub) {
      bf16x8 Af = *(const bf16x8*)(&As[msub * 16 + l15][lg * 8]);
      acc[msub] = __builtin_amdgcn_mfma_f32_16x16x32_bf16(Af, Bf, acc[msub], 0, 0, 0);
    }
  }

  int nl = nt * 16 + l15;
  float* dst = nullptr; int col = 0; const float* bias_ = nullptr;
  if (nl < D_DIM)                         { dst = xl; col = nl;       bias_ = bl; }
  else if (nl >= 384 && nl < 384 + D_DIM) { dst = xr; col = nl - 384; bias_ = br; }
  if (dst) {
    float bv = bias_[col];
    #pragma unroll
    for (int msub = 0; msub < 4; ++msub) {
      #pragma unroll
      for (int r = 0; r < 4; ++r) {
        int m = m0 + msub * 16 + lg * 4 + r;
        if (m < N) dst[(size_t)m * D_DIM + col] = acc[msub][r] + bv;
      }
    }
  }
}

// ---------------- GAT attention ----------------
__device__ __forceinline__ unsigned fmap_u(float f) {
  unsigned u = __float_as_uint(f);
  return (u & 0x80000000u) ? ~u : (u | 0x80000000u);
}
__device__ __forceinline__ float fumap(unsigned u) {
  return __uint_as_float((u & 0x80000000u) ? (u ^ 0x80000000u) : ~u);
}

__global__ __launch_bounds__(256) void edge_e_kernel(
    const float* __restrict__ xl, const float* __restrict__ xr,
    const float* __restrict__ att, const int* __restrict__ ei,
    float* __restrict__ e_buf, unsigned* __restrict__ emax_u, int E)
{
  int widx = (blockIdx.x * 256 + threadIdx.x) >> 6;
  int lane = threadIdx.x & 63;
  if (widx >= E) return;
  int s = ei[widx], t = ei[E + widx];
  const float* pl = xl + (size_t)s * D_DIM;
  const float* pr = xr + (size_t)t * D_DIM;
  float acc = 0.0f;
  for (int d = lane; d < D_DIM; d += 64) {
    float m = pl[d] + pr[d];
    m = (m > 0.0f) ? m : 0.2f * m;
    acc += m * att[d];
  }
  #pragma unroll
  for (int o = 32; o > 0; o >>= 1) acc += __shfl_down(acc, o);
  if (lane == 0) {
    e_buf[widx] = acc;
    atomicMax(&emax_u[t], fmap_u(acc));
  }
}

__global__ void softmax_denom_kernel(
    const int* __restrict__ ei, float* __restrict__ e_buf,
    const unsigned* __restrict__ emax_u, float* __restrict__ denom, int E)
{
  int e = blockIdx.x * 256 + threadIdx.x;
  if (e >= E) return;
  int t = ei[E + e];
  float mx = fumap(emax_u[t]);
  float ex = __expf(e_buf[e] - mx);
  e_buf[e] = ex;
  atomicAdd(&denom[t], ex);
}

__global__ __launch_bounds__(256) void aggregate_kernel(
    const int* __restrict__ ei, const float* __restrict__ e_buf,
    const float* __restrict__ denom, const float* __restrict__ xl,
    float* __restrict__ agg, int E)
{
  int widx = (blockIdx.x * 256 + threadIdx.x) >> 6;
  int lane = threadIdx.x & 63;
  if (widx >= E) return;
  int s = ei[widx], t = ei[E + widx];
  float alpha = e_buf[widx] / (denom[t] + 1e-16f);
  const float* pl = xl + (size_t)s * D_DIM;
  float* pa = agg + (size_t)t * D_DIM;
  for (int d = lane; d < D_DIM; d += 64)
    atomicAdd(&pa[d], alpha * pl[d]);
}

__global__ void finalize_kernel(
    const float* __restrict__ agg, const float* __restrict__ x_mod,
    const float* __restrict__ bias, float* __restrict__ out, int N, int goff)
{
  int i = blockIdx.x * 256 + threadIdx.x;
  int total = N * D_DIM;
  if (i >= total) return;
  int n = i / D_DIM;
  int d = i - n * D_DIM;
  float v = agg[i] + bias[d] + x_mod[i];
  out[(size_t)n * (2 * D_DIM) + goff + d] = fmaxf(v, 0.0f);
}

// ---------------------------------------------------------------------------
extern "C" void kernel_launch(void* const* d_in, const int* in_sizes, int n_in,
                              void* d_out, int out_size, void* d_ws, size_t ws_size,
                              hipStream_t stream)
{
  const float* fx     = (const float*)d_in[0];
  const float* bx     = (const float*)d_in[1];
  const int*   fei    = (const int*)d_in[2];
  const int*   bei    = (const int*)d_in[3];
  const int*   ftk    = (const int*)d_in[4];
  const int*   btk    = (const int*)d_in[5];
  const float* embed  = (const float*)d_in[6];
  const float* Wih_f  = (const float*)d_in[7];
  const float* Whh_f  = (const float*)d_in[8];
  const float* bih_f  = (const float*)d_in[9];
  const float* bhh_f  = (const float*)d_in[10];
  const float* Wih_r  = (const float*)d_in[11];
  // d_in[12] = Whh_r : unused (reverse cell consumes zero state)
  const float* bih_r  = (const float*)d_in[13];
  const float* bhh_r  = (const float*)d_in[14];
  const float* W1     = (const float*)d_in[15];
  const float* b1     = (const float*)d_in[16];
  const float* W2     = (const float*)d_in[17];
  const float* b2     = (const float*)d_in[18];

  const float* Wl_g[2]   = {(const float*)d_in[19], (const float*)d_in[25]};
  const float* bl_g[2]   = {(const float*)d_in[20], (const float*)d_in[26]};
  const float* Wr_g[2]   = {(const float*)d_in[21], (const float*)d_in[27]};
  const float* br_g[2]   = {(const float*)d_in[22], (const float*)d_in[28]};
  const float* att_g[2]  = {(const float*)d_in[23], (const float*)d_in[29]};
  const float* bias_g[2] = {(const float*)d_in[24], (const float*)d_in[30]};
  const float* x_g[2]    = {fx, bx};
  const int*   ei_g[2]   = {fei, bei};
  const int*   tk_g[2]   = {ftk, btk};

  const int E = in_sizes[2] / 2;          // 400000
  const int N = in_sizes[0] / D_DIM;      // 50000

  // ---- workspace layout (byte-based, 256B aligned chunks) ----
  char* wsb = (char*)d_ws;
  size_t off = 0;
  auto alloc = [&](size_t bytes) -> void* {
    void* p = wsb + off; off += (bytes + 255) & ~(size_t)255; return p;
  };
  unsigned short* Pg     = (unsigned short*)alloc((size_t)64 * 128 * 4 * 2);
  unsigned short* BfragW = (unsigned short*)alloc((size_t)65536 * 2);
  unsigned short* Bfrag1 = (unsigned short*)alloc((size_t)4096 * 2);
  unsigned short* Wfrag2 = (unsigned short*)alloc((size_t)2 * 294912 * 2);
  float* FB    = (float*)alloc((size_t)64 * 32 * 4);
  float* ea    = (float*)alloc((size_t)E * 4);
  float* ebuf  = (float*)alloc((size_t)E * 4);
  int*   srcid = (int*)alloc((size_t)E * 4);
  int*   tgtid = (int*)alloc((size_t)E * 4);
  unsigned* emaxu = (unsigned*)alloc((size_t)N * 4);
  float* denom = (float*)alloc((size_t)N * 4);
  int* win_in  = (int*)alloc((size_t)N * SID_N * 4);
  int* win_out = (int*)alloc((size_t)N * SID_N * 4);
  float* xmod  = (float*)alloc((size_t)N * D_DIM * 4);
  float* xl    = (float*)alloc((size_t)N * D_DIM * 4);
  float* xr    = (float*)alloc((size_t)N * D_DIM * 4);   // reused as agg
  (void)ws_size; (void)n_in; (void)out_size;

  // span-exact fill counts (include alignment padding between buffers):
  const size_t emax_denom_u32 = (size_t)((char*)denom - (char*)emaxu) / 4 + N;
  const size_t win_u32        = (size_t)((char*)win_out - (char*)win_in) / 4
                                + (size_t)N * SID_N;

  float* out = (float*)d_out;

  precompute_kernel<<<64, 512, 0, stream>>>(
      embed, Wih_f, Whh_f, bih_f, bhh_f, Wih_r, bih_r, bhh_r, W1, b1,
      Pg, BfragW, Bfrag1, FB);
  pack_w_kernel<<<(294912 + 255) / 256, 256, 0, stream>>>(
      Wl_g[0], Wr_g[0], Wfrag2);
  pack_w_kernel<<<(294912 + 255) / 256, 256, 0, stream>>>(
      Wl_g[1], Wr_g[1], Wfrag2 + 294912);

  const int nTiles  = (E + 15) / 16;
  const int gridL   = nTiles < 2048 ? nTiles : 2048;
  const int gridE   = (E + 255) / 256;
  const int gridEW  = (E + 3) / 4;
  const int gridFin = (N * D_DIM + 255) / 256;
  dim3 gridG((N + 63) / 64, 12);

  for (int g = 0; g < 2; ++g) {
    const float* x  = x_g[g];
    const int*   ei = ei_g[g];

    // (1) edge scalar via MFMA LSTM
    lstm_mfma_kernel<<<gridL, 512, 0, stream>>>(tk_g[g], Pg, BfragW, Bfrag1,
                                                FB, W2, b2, ea, E, nTiles);

    // (2) x_mod = copy(x), then last-edge-wins scatter writes
    hipMemcpyAsync(xmod, x, (size_t)N * D_DIM * sizeof(float),
                   hipMemcpyDeviceToDevice, stream);
    fill_u32_kernel<<<2048, 256, 0, stream>>>((unsigned*)win_in, 0xFFFFFFFFu,
                                              win_u32);
    argmax_winner_kernel<<<gridE, 256, 0, stream>>>(x, ei, E, srcid, tgtid,
                                                    win_in, win_out);
    scatter_resolve_kernel<<<gridE, 256, 0, stream>>>(ei, ea, srcid, tgtid,
                                                      win_in, win_out, xmod, E);

    // (3) [xl||xr] = xmod @ [Wl||Wr] + bias  (bf16 MFMA)
    gemm_mfma_kernel<<<gridG, 256, 0, stream>>>(xmod, Wfrag2 + (size_t)g * 294912,
                                                bl_g[g], br_g[g], xl, xr, N);

    // (4) attention logits + scatter softmax
    fill_u32_kernel<<<512, 256, 0, stream>>>((unsigned*)emaxu, 0u,
                                             emax_denom_u32);
    edge_e_kernel<<<gridEW, 256, 0, stream>>>(xl, xr, att_g[g], ei, ebuf, emaxu, E);
    softmax_denom_kernel<<<gridE, 256, 0, stream>>>(ei, ebuf, emaxu, denom, E);

    // (5) aggregate (xr reused as agg, zeroed first)
    fill_u32_kernel<<<2048, 256, 0, stream>>>((unsigned*)xr, 0u, (size_t)N * D_DIM);
    aggregate_kernel<<<gridEW, 256, 0, stream>>>(ei, ebuf, denom, xl, xr, E);

    // (6) out[:, g*373 : +373] = relu(agg + bias + x_mod)
    finalize_kernel<<<gridFin, 256, 0, stream>>>(xr, xmod, bias_g[g], out, N,
                                                 g * D_DIM);
  }
}

// Round 5
// 3985.961 us; speedup vs baseline: 7.2305x; 1.2296x over previous
//
#include <hip/hip_runtime.h>
#include <cstdint>

// ---------------------------------------------------------------------------
// ForwardBackwardGNN — R5.
//   LSTM: operand-swapped MFMA (W=A, H=B) -> contiguous h-writes (b64 +
//         cvt_pk), 1 token read + 2 P-loads per step.
//   GAT:  CSR by dst + fused node kernel (softmax+aggregate+finalize),
//         no fp32 atomics in the hot path.
//   N=50000, E=400000, L=16, V=64, EMB=32, H=128, D=373, SID=53.
// ---------------------------------------------------------------------------

#define D_DIM   373
#define SID_N   53
#define IN_COL  161
#define OUT_COL 320
#define HS_STRIDE 136   // u16/row: 272 B, 16B-aligned, dword stride ≡ 4 mod 32

typedef short bf16x8 __attribute__((ext_vector_type(8)));
typedef float f32x4  __attribute__((ext_vector_type(4)));

#define LOG2E_F 1.4426950408889634f
#define TWO_LOG2E_F 2.8853900817779268f

__device__ __forceinline__ float fast_exp2(float x) {
#if __has_builtin(__builtin_amdgcn_exp2f)
  return __builtin_amdgcn_exp2f(x);
#else
  return exp2f(x);
#endif
}
__device__ __forceinline__ float fast_rcp(float x) {
#if __has_builtin(__builtin_amdgcn_rcpf)
  return __builtin_amdgcn_rcpf(x);
#else
  return 1.0f / x;
#endif
}
// pre-scaled: input already times -log2e (sig) / +2log2e (tanh)
__device__ __forceinline__ float sig_pre(float y)  { return fast_rcp(1.0f + fast_exp2(y)); }
__device__ __forceinline__ float tanh_pre(float y) { return 1.0f - 2.0f * fast_rcp(1.0f + fast_exp2(y)); }
__device__ __forceinline__ float tanh_pl(float x)  { return tanh_pre(TWO_LOG2E_F * x); }

__device__ __forceinline__ float sig_ref(float x)  { return 1.0f / (1.0f + __expf(-x)); }
__device__ __forceinline__ float tanh_ref(float x) { return 2.0f / (1.0f + __expf(-2.0f * x)) - 1.0f; }

__device__ __forceinline__ unsigned short f2bf(float f) {
  unsigned u = __float_as_uint(f);
  unsigned r = (u + 0x7fffu + ((u >> 16) & 1u)) >> 16;
  return (unsigned short)r;
}
__device__ __forceinline__ float bflo2f(unsigned u) { return __uint_as_float(u << 16); }
__device__ __forceinline__ float bfhi2f(unsigned u) { return __uint_as_float(u & 0xffff0000u); }
__device__ __forceinline__ unsigned cvt_pk_bf16(float lo, float hi) {
  unsigned r;
  asm("v_cvt_pk_bf16_f32 %0, %1, %2" : "=v"(r) : "v"(lo), "v"(hi));
  return r;
}

// ---------------- generic fill ----------------
__global__ void fill_u32_kernel(unsigned* __restrict__ p, unsigned v, size_t n) {
  size_t i = (size_t)blockIdx.x * blockDim.x + threadIdx.x;
  size_t stride = (size_t)gridDim.x * blockDim.x;
  for (; i < n; i += stride) p[i] = v;
}

// ---------------- precompute: Pg / FB / MFMA fragments ----------------
// grid = 64, block = 512. Pg/BfragW carry folded scales (i,f,o:-log2e; g:+2log2e).
__global__ void precompute_kernel(
    const float* __restrict__ embed, const float* __restrict__ Wih_f,
    const float* __restrict__ Whh_f,
    const float* __restrict__ bih_f, const float* __restrict__ bhh_f,
    const float* __restrict__ Wih_r,
    const float* __restrict__ bih_r, const float* __restrict__ bhh_r,
    const float* __restrict__ W1, const float* __restrict__ b1,
    unsigned short* __restrict__ Pg, unsigned short* __restrict__ BfragW,
    unsigned short* __restrict__ Bfrag1, float* __restrict__ FB)
{
  __shared__ float ps[512];
  __shared__ float gb[512];
  __shared__ float hb[128];
  int v = blockIdx.x;
  int j = threadIdx.x;

  float s = 0.0f;
  if (v != 0) {
    #pragma unroll
    for (int k = 0; k < 32; ++k) s += embed[v * 32 + k] * Wih_f[j * 32 + k];
  }
  ps[j] = s + bih_f[j] + bhh_f[j];

  float gr = bih_r[j] + bhh_r[j];
  if (v != 0) {
    #pragma unroll
    for (int k = 0; k < 32; ++k) gr += embed[v * 32 + k] * Wih_r[j * 32 + k];
  }
  gb[j] = gr;
  __syncthreads();
  if (j < 128) {
    float c = sig_ref(gb[j]) * tanh_ref(gb[256 + j]);
    hb[j] = sig_ref(gb[384 + j]) * tanh_ref(c);
  }
  __syncthreads();

  // Pg[v][h][g] = bf16(scale(g) * P[v][g*128+h])
  { int h = j >> 2, g = j & 3;
    float sc = (g == 2) ? TWO_LOG2E_F : -LOG2E_F;
    Pg[((size_t)v * 128 + h) * 4 + g] = f2bf(ps[g * 128 + h] * sc); }

  if (j < 32) {
    float s2 = b1[j];
    for (int m = 0; m < 128; ++m) s2 += hb[m] * W1[(128 + m) * 32 + j];
    FB[v * 32 + j] = s2;
  }

  if (v == 0) {
    // BfragW flat = ((nt*4+ks)*64 + lane)*8 + e ; val = scale * Whh_f[n][k]
    // n = nt*16 + (l&15), k = ks*32 + (l>>4)*8 + e, nt = gate*8 + wv2
    for (int f = j; f < 65536; f += 512) {
      int e = f & 7, l = (f >> 3) & 63, ks = (f >> 9) & 3, nt = f >> 11;
      int n = nt * 16 + (l & 15);
      int k = ks * 32 + (l >> 4) * 8 + e;
      float sc = ((nt >> 3) == 2) ? TWO_LOG2E_F : -LOG2E_F;
      BfragW[f] = f2bf(Whh_f[(size_t)n * 128 + k] * sc);
    }
  }
  if (v == 1) {
    // Bfrag1 flat = ((n2*4+ks)*64 + lane)*8 + e ; B[k][q] = W1[k][q] (k<128)
    for (int f = j; f < 4096; f += 512) {
      int e = f & 7, l = (f >> 3) & 63, ks = (f >> 9) & 3, n2 = f >> 11;
      int q = n2 * 16 + (l & 15);
      int k = ks * 32 + (l >> 4) * 8 + e;
      Bfrag1[f] = f2bf(W1[(size_t)k * 32 + q]);
    }
  }
}

// ---------------- MFMA LSTM (operand-swapped): 16 edges/block, 8 waves ------
// mfma(A=W-frag, B=H-frag) -> D[gatecol][edge]: col=lane&15=edge,
// row=(lane>>4)*4+reg = hcol_local. Wave wv2 owns hcols [wv2*16,+16) x 4 gates.
// Lane (l15,lg): edge=l15, hcols wv2*16+lg*4+r (r=0..3) -> contiguous h-writes.
__global__ __launch_bounds__(512, 4) void lstm_mfma_kernel(
    const int*   __restrict__ tokens,   // [E][16]
    const unsigned short* __restrict__ Pg,      // [64][128][4] bf16 (scaled)
    const unsigned short* __restrict__ BfragW,  // [32][4][64][8] bf16 (scaled)
    const unsigned short* __restrict__ Bfrag1,  // [2][4][64][8] bf16
    const float* __restrict__ FB,       // [64][32]
    const float* __restrict__ W2,       // [32]
    const float* __restrict__ b2,
    float* __restrict__ ea, int E, int nTiles)
{
  __shared__ unsigned short Hs[2][16 * HS_STRIDE];   // [edge][hid]
  __shared__ int toks[16][16];          // [t][edge]

  int tid  = threadIdx.x;
  int lane = tid & 63;
  int wv2  = tid >> 6;                  // 0..7
  int l15  = lane & 15;                 // edge
  int lg   = lane >> 4;                 // 0..3
  int hbase = wv2 * 16 + lg * 4;        // this lane's 4 hcols

  // persistent A-frags (W): BW[gate][ks]
  bf16x8 BW[4][4];
  #pragma unroll
  for (int gate = 0; gate < 4; ++gate)
    #pragma unroll
    for (int ks = 0; ks < 4; ++ks)
      BW[gate][ks] = *(const bf16x8*)(BfragW +
          ((size_t)((gate * 8 + wv2) * 4 + ks) * 64 + lane) * 8);
  float4 w2lo = *(const float4*)(W2 + lg * 4);        // q = lg*4+r
  float4 w2hi = *(const float4*)(W2 + 16 + lg * 4);   // q = 16+lg*4+r
  float b2v = b2[0];

  for (int tile = blockIdx.x; tile < nTiles; tile += gridDim.x) {
    int e0 = tile * 16;
    if (tid < 256) {                    // stage tokens [t][m]
      int m = tid >> 4, t = tid & 15;
      int ee = e0 + m; if (ee >= E) ee = E - 1;
      toks[t][m] = tokens[(size_t)ee * 16 + t];
    }
    __syncthreads();

    float cst[4];
    // ---- step 0: gates = P only (h0=c0=0, f-term vanishes)
    {
      int v0 = toks[0][l15];
      const uint4* pp = (const uint4*)(Pg + ((size_t)v0 * 128 + hbase) * 4);
      uint4 pa = pp[0], pb = pp[1];     // pos p=r*4+g: word p>>1, half p&1
      float h[4];
      {
        float ii = sig_pre(bflo2f(pa.x)), gg = tanh_pre(bflo2f(pa.y));
        float oo = sig_pre(bfhi2f(pa.y));
        float cn = ii * gg; cst[0] = cn; h[0] = oo * tanh_pl(cn);
      }
      {
        float ii = sig_pre(bflo2f(pa.z)), gg = tanh_pre(bflo2f(pa.w));
        float oo = sig_pre(bfhi2f(pa.w));
        float cn = ii * gg; cst[1] = cn; h[1] = oo * tanh_pl(cn);
      }
      {
        float ii = sig_pre(bflo2f(pb.x)), gg = tanh_pre(bflo2f(pb.y));
        float oo = sig_pre(bfhi2f(pb.y));
        float cn = ii * gg; cst[2] = cn; h[2] = oo * tanh_pl(cn);
      }
      {
        float ii = sig_pre(bflo2f(pb.z)), gg = tanh_pre(bflo2f(pb.w));
        float oo = sig_pre(bfhi2f(pb.w));
        float cn = ii * gg; cst[3] = cn; h[3] = oo * tanh_pl(cn);
      }
      uint2 hp = make_uint2(cvt_pk_bf16(h[0], h[1]), cvt_pk_bf16(h[2], h[3]));
      *(uint2*)(&Hs[0][l15 * HS_STRIDE + hbase]) = hp;
    }
    __syncthreads();

    int cur = 0;
    #pragma unroll 1
    for (int t = 1; t < 16; ++t) {
      int vt = toks[t][l15];
      const uint4* pp = (const uint4*)(Pg + ((size_t)vt * 128 + hbase) * 4);
      uint4 pa = pp[0], pb = pp[1];
      f32x4 acc[4];
      acc[0] = (f32x4){bflo2f(pa.x), bflo2f(pa.z), bflo2f(pb.x), bflo2f(pb.z)}; // i
      acc[1] = (f32x4){bfhi2f(pa.x), bfhi2f(pa.z), bfhi2f(pb.x), bfhi2f(pb.z)}; // f
      acc[2] = (f32x4){bflo2f(pa.y), bflo2f(pa.w), bflo2f(pb.y), bflo2f(pb.w)}; // g
      acc[3] = (f32x4){bfhi2f(pa.y), bfhi2f(pa.w), bfhi2f(pb.y), bfhi2f(pb.w)}; // o

      bf16x8 Hf[4];
      #pragma unroll
      for (int ks = 0; ks < 4; ++ks)
        Hf[ks] = *(const bf16x8*)(&Hs[cur][l15 * HS_STRIDE + ks * 32 + lg * 8]);
      #pragma unroll
      for (int ks = 0; ks < 4; ++ks)
        #pragma unroll
        for (int gate = 0; gate < 4; ++gate)
          acc[gate] = __builtin_amdgcn_mfma_f32_16x16x32_bf16(
              BW[gate][ks], Hf[ks], acc[gate], 0, 0, 0);

      float h[4];
      #pragma unroll
      for (int r = 0; r < 4; ++r) {
        float ii = sig_pre(acc[0][r]);
        float ff = sig_pre(acc[1][r]);
        float gg = tanh_pre(acc[2][r]);
        float oo = sig_pre(acc[3][r]);
        float cn = fmaf(ff, cst[r], ii * gg);
        cst[r] = cn;
        h[r] = oo * tanh_pl(cn);
      }
      uint2 hp = make_uint2(cvt_pk_bf16(h[0], h[1]), cvt_pk_bf16(h[2], h[3]));
      *(uint2*)(&Hs[cur ^ 1][l15 * HS_STRIDE + hbase]) = hp;
      cur ^= 1;
      __syncthreads();
    }

    // ---- tail (wave 0): feat = relu(h15 @ W1[:128] + FB[tok15]);
    //      ea = relu(feat . W2 + b2).  acc2: row=q_local, col=edge.
    if (wv2 == 0) {
      bf16x8 Hf[4];
      #pragma unroll
      for (int ks = 0; ks < 4; ++ks)
        Hf[ks] = *(const bf16x8*)(&Hs[cur][l15 * HS_STRIDE + ks * 32 + lg * 8]);
      f32x4 a2[2];
      a2[0] = (f32x4){0.f, 0.f, 0.f, 0.f};
      a2[1] = (f32x4){0.f, 0.f, 0.f, 0.f};
      #pragma unroll
      for (int ks = 0; ks < 4; ++ks)
        #pragma unroll
        for (int n2 = 0; n2 < 2; ++n2)
          a2[n2] = __builtin_amdgcn_mfma_f32_16x16x32_bf16(
              *(const bf16x8*)(Bfrag1 + ((size_t)(n2 * 4 + ks) * 64 + lane) * 8),
              Hf[ks], a2[n2], 0, 0, 0);
      int v15 = toks[15][l15];
      float4 fb0 = *(const float4*)(FB + v15 * 32 + lg * 4);
      float4 fb1 = *(const float4*)(FB + v15 * 32 + 16 + lg * 4);
      float pr = fmaxf(a2[0][0] + fb0.x, 0.f) * w2lo.x
               + fmaxf(a2[0][1] + fb0.y, 0.f) * w2lo.y
               + fmaxf(a2[0][2] + fb0.z, 0.f) * w2lo.z
               + fmaxf(a2[0][3] + fb0.w, 0.f) * w2lo.w
               + fmaxf(a2[1][0] + fb1.x, 0.f) * w2hi.x
               + fmaxf(a2[1][1] + fb1.y, 0.f) * w2hi.y
               + fmaxf(a2[1][2] + fb1.z, 0.f) * w2hi.z
               + fmaxf(a2[1][3] + fb1.w, 0.f) * w2hi.w;
      pr += __shfl_xor(pr, 16);
      pr += __shfl_xor(pr, 32);
      int eidx = e0 + l15;
      if (lane < 16 && eidx < E) ea[eidx] = fmaxf(pr + b2v, 0.0f);
    }
    __syncthreads();   // before next tile reuses toks/Hs
  }
}

// ---------------- argmax ids + scatter winner (last edge wins) ----------------
__global__ void argmax_winner_kernel(
    const float* __restrict__ x, const int* __restrict__ ei, int E,
    int* __restrict__ srcid, int* __restrict__ tgtid,
    int* __restrict__ win_in, int* __restrict__ win_out)
{
  int e = blockIdx.x * 256 + threadIdx.x;
  if (e >= E) return;
  int s = ei[e];
  int t = ei[E + e];
  const float* xs = x + (size_t)s * D_DIM;
  int sid = 0; float bv = xs[0];
  for (int k = 1; k < SID_N; ++k) { float v = xs[k]; if (v > bv) { bv = v; sid = k; } }
  const float* xt = x + (size_t)t * D_DIM;
  int tix = 0; bv = xt[0];
  for (int k = 1; k < SID_N; ++k) { float v = xt[k]; if (v > bv) { bv = v; tix = k; } }
  srcid[e] = sid;
  tgtid[e] = tix;
  atomicMax(&win_in[(size_t)t * SID_N + sid], e);
  atomicMax(&win_out[(size_t)s * SID_N + tix], e);
}

__global__ void scatter_resolve_kernel(
    const int* __restrict__ ei, const float* __restrict__ ea,
    const int* __restrict__ srcid, const int* __restrict__ tgtid,
    const int* __restrict__ win_in, const int* __restrict__ win_out,
    float* __restrict__ x_mod, int E)
{
  int e = blockIdx.x * 256 + threadIdx.x;
  if (e >= E) return;
  int s = ei[e];
  int t = ei[E + e];
  int sid = srcid[e], tix = tgtid[e];
  if (win_in[(size_t)t * SID_N + sid] == e)
    x_mod[(size_t)t * D_DIM + IN_COL + sid] = ea[e];
  if (win_out[(size_t)s * SID_N + tix] == e)
    x_mod[(size_t)s * D_DIM + OUT_COL + tix] = ea[e];
}

// ---------------- pack Wl||Wr into MFMA fragment order ----------------
__global__ void pack_w_kernel(const float* __restrict__ Wl,
                              const float* __restrict__ Wr,
                              unsigned short* __restrict__ Wfrag)
{
  int f = blockIdx.x * 256 + threadIdx.x;
  if (f >= 48 * 12 * 64 * 8) return;
  int e = f & 7, l = (f >> 3) & 63;
  int rest = f >> 9;
  int ks = rest % 12, nt = rest / 12;
  int nl = nt * 16 + (l & 15);
  int k  = ks * 32 + (l >> 4) * 8 + e;
  float val = 0.0f;
  if (k < D_DIM) {
    if (nl < D_DIM)                      val = Wl[(size_t)k * D_DIM + nl];
    else if (nl >= 384 && nl < 384 + D_DIM) val = Wr[(size_t)k * D_DIM + (nl - 384)];
  }
  Wfrag[f] = f2bf(val);
}

// ---------------- fused bf16 MFMA GEMM: [xl||xr] = xmod @ [Wl||Wr] + bias ----
__global__ __launch_bounds__(256, 2) void gemm_mfma_kernel(
    const float* __restrict__ A,               // xmod [N][373] fp32
    const unsigned short* __restrict__ Wfrag,  // [48][12][64][8] bf16
    const float* __restrict__ bl, const float* __restrict__ br,
    float* __restrict__ xl, float* __restrict__ xr, int N)
{
  __shared__ unsigned short As[64][40];
  int tid  = threadIdx.x;
  int lane = tid & 63;
  int wv   = tid >> 6;
  int l15  = lane & 15, lg = lane >> 4;
  int m0   = blockIdx.x * 64;
  int nt   = blockIdx.y * 4 + wv;

  f32x4 acc[4];
  #pragma unroll
  for (int i = 0; i < 4; ++i) acc[i] = (f32x4){0.f, 0.f, 0.f, 0.f};

  int srow = tid >> 2, seg = tid & 3;
  int gr = m0 + srow; if (gr >= N) gr = N - 1;
  const float* arow = A + (size_t)gr * D_DIM;

  for (int ks = 0; ks < 12; ++ks) {
    int c0 = ks * 32 + seg * 8;
    float v[8];
    #pragma unroll
    for (int j = 0; j < 8; ++j) v[j] = (c0 + j < D_DIM) ? arow[c0 + j] : 0.0f;
    unsigned pk0 = cvt_pk_bf16(v[0], v[1]);
    unsigned pk1 = cvt_pk_bf16(v[2], v[3]);
    unsigned pk2 = cvt_pk_bf16(v[4], v[5]);
    unsigned pk3 = cvt_pk_bf16(v[6], v[7]);
    __syncthreads();
    *(uint4*)(&As[srow][seg * 8]) = make_uint4(pk0, pk1, pk2, pk3);
    __syncthreads();

    bf16x8 Bf = *(const bf16x8*)(Wfrag + ((size_t)(nt * 12 + ks) * 64 + lane) * 8);
    #pragma unroll
    for (int msub = 0; msub < 4; ++msub) {
      bf16x8 Af = *(const bf16x8*)(&As[msub * 16 + l15][lg * 8]);
      acc[msub] = __builtin_amdgcn_mfma_f32_16x16x32_bf16(Af, Bf, acc[msub], 0, 0, 0);
    }
  }

  int nl = nt * 16 + l15;
  float* dst = nullptr; int col = 0; const float* bias_ = nullptr;
  if (nl < D_DIM)                         { dst = xl; col = nl;       bias_ = bl; }
  else if (nl >= 384 && nl < 384 + D_DIM) { dst = xr; col = nl - 384; bias_ = br; }
  if (dst) {
    float bv = bias_[col];
    #pragma unroll
    for (int msub = 0; msub < 4; ++msub) {
      #pragma unroll
      for (int r = 0; r < 4; ++r) {
        int m = m0 + msub * 16 + lg * 4 + r;
        if (m < N) dst[(size_t)m * D_DIM + col] = acc[msub][r] + bv;
      }
    }
  }
}

// ---------------- GAT: attention logits (no atomics) ----------------
__global__ __launch_bounds__(256) void edge_e_kernel(
    const float* __restrict__ xl, const float* __restrict__ xr,
    const float* __restrict__ att, const int* __restrict__ ei,
    float* __restrict__ e_buf, int E)
{
  int widx = (blockIdx.x * 256 + threadIdx.x) >> 6;
  int lane = threadIdx.x & 63;
  if (widx >= E) return;
  int s = ei[widx], t = ei[E + widx];
  const float* pl = xl + (size_t)s * D_DIM;
  const float* pr = xr + (size_t)t * D_DIM;
  float acc = 0.0f;
  for (int d = lane; d < D_DIM; d += 64) {
    float m = pl[d] + pr[d];
    m = (m > 0.0f) ? m : 0.2f * m;
    acc += m * att[d];
  }
  #pragma unroll
  for (int o = 32; o > 0; o >>= 1) acc += __shfl_down(acc, o);
  if (lane == 0) e_buf[widx] = acc;
}

// ---------------- CSR build: histogram / scan / placement ----------------
__global__ void hist_kernel(const int* __restrict__ ei, unsigned* __restrict__ deg,
                            int E) {
  int e = blockIdx.x * 256 + threadIdx.x;
  if (e >= E) return;
  atomicAdd(&deg[ei[E + e]], 1u);
}

__global__ void scan1_kernel(const unsigned* __restrict__ deg,
                             unsigned* __restrict__ excl,
                             unsigned* __restrict__ bsum, int n) {
  __shared__ unsigned s[256];
  int t = threadIdx.x;
  int i = blockIdx.x * 256 + t;
  unsigned v = (i < n) ? deg[i] : 0u;
  s[t] = v; __syncthreads();
  #pragma unroll
  for (int o = 1; o < 256; o <<= 1) {
    unsigned u = (t >= o) ? s[t - o] : 0u;
    __syncthreads();
    s[t] += u;
    __syncthreads();
  }
  if (i < n) excl[i] = s[t] - v;
  if (t == 255) bsum[blockIdx.x] = s[255];
}

__global__ void scan2_kernel(unsigned* __restrict__ bsum, int nb) {
  __shared__ unsigned s[256];
  int t = threadIdx.x;
  unsigned v = (t < nb) ? bsum[t] : 0u;
  s[t] = v; __syncthreads();
  #pragma unroll
  for (int o = 1; o < 256; o <<= 1) {
    unsigned u = (t >= o) ? s[t - o] : 0u;
    __syncthreads();
    s[t] += u;
    __syncthreads();
  }
  if (t < nb) bsum[t] = s[t] - v;   // exclusive
}

__global__ void scan3_kernel(unsigned* __restrict__ excl,
                             const unsigned* __restrict__ bsum, int n) {
  int i = blockIdx.x * 256 + threadIdx.x;
  if (i < n) excl[i] += bsum[i >> 8];
}

__global__ void place_kernel(const int* __restrict__ ei,
                             unsigned* __restrict__ offs,
                             int* __restrict__ csr_eid, int E) {
  int e = blockIdx.x * 256 + threadIdx.x;
  if (e >= E) return;
  unsigned j = atomicAdd(&offs[ei[E + e]], 1u);
  csr_eid[j] = e;
}

// ---------------- fused per-node: softmax + aggregate + finalize ----------
// wave per node. After place_kernel, offs[n] = end; start = end - deg[n].
__global__ __launch_bounds__(256) void node_gat_kernel(
    const int* __restrict__ ei, const int* __restrict__ csr_eid,
    const unsigned* __restrict__ offs, const unsigned* __restrict__ deg,
    const float* __restrict__ ebuf, const float* __restrict__ xl,
    const float* __restrict__ xmod, const float* __restrict__ bias,
    float* __restrict__ out, int N, int E, int goff)
{
  int n = (blockIdx.x * 256 + threadIdx.x) >> 6;
  int lane = threadIdx.x & 63;
  if (n >= N) return;
  unsigned end = offs[n], d = deg[n], start = end - d;

  float mx = -3.4e38f;
  for (unsigned j = start; j < end; ++j)
    mx = fmaxf(mx, ebuf[csr_eid[j]]);
  float den = 0.0f;
  for (unsigned j = start; j < end; ++j)
    den += __expf(ebuf[csr_eid[j]] - mx);
  float inv = 1.0f / (den + 1e-16f);

  float o0 = 0, o1 = 0, o2 = 0, o3 = 0, o4 = 0, o5 = 0;
  for (unsigned j = start; j < end; ++j) {
    int eid = csr_eid[j];
    float w = __expf(ebuf[eid] - mx) * inv;
    const float* row = xl + (size_t)ei[eid] * D_DIM;
    o0 = fmaf(w, row[lane], o0);
    o1 = fmaf(w, row[64 + lane], o1);
    o2 = fmaf(w, row[128 + lane], o2);
    o3 = fmaf(w, row[192 + lane], o3);
    o4 = fmaf(w, row[256 + lane], o4);
    if (lane < 53) o5 = fmaf(w, row[320 + lane], o5);
  }

  const float* xm = xmod + (size_t)n * D_DIM;
  float* op = out + (size_t)n * (2 * D_DIM) + goff;
  op[lane]       = fmaxf(o0 + bias[lane]       + xm[lane],       0.0f);
  op[64 + lane]  = fmaxf(o1 + bias[64 + lane]  + xm[64 + lane],  0.0f);
  op[128 + lane] = fmaxf(o2 + bias[128 + lane] + xm[128 + lane], 0.0f);
  op[192 + lane] = fmaxf(o3 + bias[192 + lane] + xm[192 + lane], 0.0f);
  op[256 + lane] = fmaxf(o4 + bias[256 + lane] + xm[256 + lane], 0.0f);
  if (lane < 53)
    op[320 + lane] = fmaxf(o5 + bias[320 + lane] + xm[320 + lane], 0.0f);
}

// ---------------------------------------------------------------------------
extern "C" void kernel_launch(void* const* d_in, const int* in_sizes, int n_in,
                              void* d_out, int out_size, void* d_ws, size_t ws_size,
                              hipStream_t stream)
{
  const float* fx     = (const float*)d_in[0];
  const float* bx     = (const float*)d_in[1];
  const int*   fei    = (const int*)d_in[2];
  const int*   bei    = (const int*)d_in[3];
  const int*   ftk    = (const int*)d_in[4];
  const int*   btk    = (const int*)d_in[5];
  const float* embed  = (const float*)d_in[6];
  const float* Wih_f  = (const float*)d_in[7];
  const float* Whh_f  = (const float*)d_in[8];
  const float* bih_f  = (const float*)d_in[9];
  const float* bhh_f  = (const float*)d_in[10];
  const float* Wih_r  = (const float*)d_in[11];
  // d_in[12] = Whh_r : unused (reverse cell consumes zero state)
  const float* bih_r  = (const float*)d_in[13];
  const float* bhh_r  = (const float*)d_in[14];
  const float* W1     = (const float*)d_in[15];
  const float* b1     = (const float*)d_in[16];
  const float* W2     = (const float*)d_in[17];
  const float* b2     = (const float*)d_in[18];

  const float* Wl_g[2]   = {(const float*)d_in[19], (const float*)d_in[25]};
  const float* bl_g[2]   = {(const float*)d_in[20], (const float*)d_in[26]};
  const float* Wr_g[2]   = {(const float*)d_in[21], (const float*)d_in[27]};
  const float* br_g[2]   = {(const float*)d_in[22], (const float*)d_in[28]};
  const float* att_g[2]  = {(const float*)d_in[23], (const float*)d_in[29]};
  const float* bias_g[2] = {(const float*)d_in[24], (const float*)d_in[30]};
  const float* x_g[2]    = {fx, bx};
  const int*   ei_g[2]   = {fei, bei};
  const int*   tk_g[2]   = {ftk, btk};

  const int E = in_sizes[2] / 2;          // 400000
  const int N = in_sizes[0] / D_DIM;      // 50000
  (void)att_g;

  // ---- workspace layout (byte-based, 256B aligned chunks) ----
  char* wsb = (char*)d_ws;
  size_t off = 0;
  auto alloc = [&](size_t bytes) -> void* {
    void* p = wsb + off; off += (bytes + 255) & ~(size_t)255; return p;
  };
  unsigned short* Pg     = (unsigned short*)alloc((size_t)64 * 128 * 4 * 2);
  unsigned short* BfragW = (unsigned short*)alloc((size_t)65536 * 2);
  unsigned short* Bfrag1 = (unsigned short*)alloc((size_t)4096 * 2);
  unsigned short* Wfrag2 = (unsigned short*)alloc((size_t)2 * 294912 * 2);
  float* FB    = (float*)alloc((size_t)64 * 32 * 4);
  float* ea    = (float*)alloc((size_t)E * 4);
  float* ebuf  = (float*)alloc((size_t)E * 4);
  int*   srcid = (int*)alloc((size_t)E * 4);
  int*   tgtid = (int*)alloc((size_t)E * 4);
  int*   csr_eid = (int*)alloc((size_t)E * 4);
  unsigned* deg  = (unsigned*)alloc((size_t)N * 4);
  unsigned* offs = (unsigned*)alloc((size_t)N * 4);
  unsigned* bsum = (unsigned*)alloc((size_t)256 * 4);
  int* win_in  = (int*)alloc((size_t)N * SID_N * 4);
  int* win_out = (int*)alloc((size_t)N * SID_N * 4);
  float* xmod  = (float*)alloc((size_t)N * D_DIM * 4);
  float* xl    = (float*)alloc((size_t)N * D_DIM * 4);
  float* xr    = (float*)alloc((size_t)N * D_DIM * 4);
  (void)ws_size; (void)n_in; (void)out_size;

  const size_t win_u32 = (size_t)((char*)win_out - (char*)win_in) / 4
                         + (size_t)N * SID_N;

  float* out = (float*)d_out;

  precompute_kernel<<<64, 512, 0, stream>>>(
      embed, Wih_f, Whh_f, bih_f, bhh_f, Wih_r, bih_r, bhh_r, W1, b1,
      Pg, BfragW, Bfrag1, FB);
  pack_w_kernel<<<(294912 + 255) / 256, 256, 0, stream>>>(
      Wl_g[0], Wr_g[0], Wfrag2);
  pack_w_kernel<<<(294912 + 255) / 256, 256, 0, stream>>>(
      Wl_g[1], Wr_g[1], Wfrag2 + 294912);

  const int nTiles  = (E + 15) / 16;
  const int gridL   = nTiles < 2048 ? nTiles : 2048;
  const int gridE   = (E + 255) / 256;
  const int gridEW  = (E + 3) / 4;
  const int nScanB  = (N + 255) / 256;          // 196 <= 256
  const int gridNd  = (N * 64 + 255) / 256;     // wave per node
  dim3 gridG((N + 63) / 64, 12);

  for (int g = 0; g < 2; ++g) {
    const float* x  = x_g[g];
    const int*   ei = ei_g[g];

    // (1) edge scalar via MFMA LSTM
    lstm_mfma_kernel<<<gridL, 512, 0, stream>>>(tk_g[g], Pg, BfragW, Bfrag1,
                                                FB, W2, b2, ea, E, nTiles);

    // (2) x_mod = copy(x), then last-edge-wins scatter writes
    hipMemcpyAsync(xmod, x, (size_t)N * D_DIM * sizeof(float),
                   hipMemcpyDeviceToDevice, stream);
    fill_u32_kernel<<<2048, 256, 0, stream>>>((unsigned*)win_in, 0xFFFFFFFFu,
                                              win_u32);
    argmax_winner_kernel<<<gridE, 256, 0, stream>>>(x, ei, E, srcid, tgtid,
                                                    win_in, win_out);
    scatter_resolve_kernel<<<gridE, 256, 0, stream>>>(ei, ea, srcid, tgtid,
                                                      win_in, win_out, xmod, E);

    // (3) [xl||xr] = xmod @ [Wl||Wr] + bias  (bf16 MFMA)
    gemm_mfma_kernel<<<gridG, 256, 0, stream>>>(xmod, Wfrag2 + (size_t)g * 294912,
                                                bl_g[g], br_g[g], xl, xr, N);

    // (4) CSR by dst
    fill_u32_kernel<<<512, 256, 0, stream>>>(deg, 0u, (size_t)N);
    hist_kernel<<<gridE, 256, 0, stream>>>(ei, deg, E);
    scan1_kernel<<<nScanB, 256, 0, stream>>>(deg, offs, bsum, N);
    scan2_kernel<<<1, 256, 0, stream>>>(bsum, nScanB);
    scan3_kernel<<<nScanB, 256, 0, stream>>>(offs, bsum, N);
    place_kernel<<<gridE, 256, 0, stream>>>(ei, offs, csr_eid, E);

    // (5) attention logits, then fused softmax+aggregate+finalize
    edge_e_kernel<<<gridEW, 256, 0, stream>>>(xl, xr, att_g[g], ei, ebuf, E);
    node_gat_kernel<<<gridNd, 256, 0, stream>>>(ei, csr_eid, offs, deg, ebuf,
                                                xl, xmod, bias_g[g], out,
                                                N, E, g * D_DIM);
  }
}

// Round 6
// 3613.935 us; speedup vs baseline: 7.9748x; 1.1029x over previous
//
#include <hip/hip_runtime.h>
#include <cstdint>

// ---------------------------------------------------------------------------
// ForwardBackwardGNN — R6.
//   LSTM: 64 edges/block (4 sub-tiles), 1 barrier/step (4x amortization);
//         paired-denominator gates: s(a)*tanh(b) = (B-1)/((1+A)(1+B)),
//         cutting trans ops 10 -> 8 per cell (5 exp2 + 3 rcp).
//   GAT:  CSR + fused node kernel (R5), exp reused between den/agg passes.
//   N=50000, E=400000, L=16, V=64, EMB=32, H=128, D=373, SID=53.
// ---------------------------------------------------------------------------

#define D_DIM   373
#define SID_N   53
#define IN_COL  161
#define OUT_COL 320
#define HS_STRIDE 136   // u16/row
#define EDGES_T 64      // edges per tile/block

typedef short bf16x8 __attribute__((ext_vector_type(8)));
typedef float f32x4  __attribute__((ext_vector_type(4)));

#define LOG2E_F 1.4426950408889634f
#define TWO_LOG2E_F 2.8853900817779268f

__device__ __forceinline__ float fast_exp2(float x) {
#if __has_builtin(__builtin_amdgcn_exp2f)
  return __builtin_amdgcn_exp2f(x);
#else
  return exp2f(x);
#endif
}
__device__ __forceinline__ float fast_rcp(float x) {
#if __has_builtin(__builtin_amdgcn_rcpf)
  return __builtin_amdgcn_rcpf(x);
#else
  return 1.0f / x;
#endif
}
__device__ __forceinline__ float sig_ref(float x)  { return 1.0f / (1.0f + __expf(-x)); }
__device__ __forceinline__ float tanh_ref(float x) { return 2.0f / (1.0f + __expf(-2.0f * x)) - 1.0f; }

__device__ __forceinline__ unsigned short f2bf(float f) {
  unsigned u = __float_as_uint(f);
  unsigned r = (u + 0x7fffu + ((u >> 16) & 1u)) >> 16;
  return (unsigned short)r;
}
__device__ __forceinline__ float bflo2f(unsigned u) { return __uint_as_float(u << 16); }
__device__ __forceinline__ float bfhi2f(unsigned u) { return __uint_as_float(u & 0xffff0000u); }
__device__ __forceinline__ unsigned cvt_pk_bf16(float lo, float hi) {
  unsigned r;
  asm("v_cvt_pk_bf16_f32 %0, %1, %2" : "=v"(r) : "v"(lo), "v"(hi));
  return r;
}
// sig(a)*tanh(b) with A=2^{-a*log2e} (pre-scaled), B=2^{+2b*log2e} (pre-scaled)
__device__ __forceinline__ float pair_sig_tanh(float A, float B) {
  return (B - 1.0f) * fast_rcp((1.0f + A) * (1.0f + B));
}

// ---------------- generic fill ----------------
__global__ void fill_u32_kernel(unsigned* __restrict__ p, unsigned v, size_t n) {
  size_t i = (size_t)blockIdx.x * blockDim.x + threadIdx.x;
  size_t stride = (size_t)gridDim.x * blockDim.x;
  for (; i < n; i += stride) p[i] = v;
}

// ---------------- precompute: Pg / FB / MFMA fragments ----------------
// grid = 64, block = 512. Pg/BfragW carry folded scales (i,f,o:-log2e; g:+2log2e).
__global__ void precompute_kernel(
    const float* __restrict__ embed, const float* __restrict__ Wih_f,
    const float* __restrict__ Whh_f,
    const float* __restrict__ bih_f, const float* __restrict__ bhh_f,
    const float* __restrict__ Wih_r,
    const float* __restrict__ bih_r, const float* __restrict__ bhh_r,
    const float* __restrict__ W1, const float* __restrict__ b1,
    unsigned short* __restrict__ Pg, unsigned short* __restrict__ BfragW,
    unsigned short* __restrict__ Bfrag1, float* __restrict__ FB)
{
  __shared__ float ps[512];
  __shared__ float gb[512];
  __shared__ float hb[128];
  int v = blockIdx.x;
  int j = threadIdx.x;

  float s = 0.0f;
  if (v != 0) {
    #pragma unroll
    for (int k = 0; k < 32; ++k) s += embed[v * 32 + k] * Wih_f[j * 32 + k];
  }
  ps[j] = s + bih_f[j] + bhh_f[j];

  float gr = bih_r[j] + bhh_r[j];
  if (v != 0) {
    #pragma unroll
    for (int k = 0; k < 32; ++k) gr += embed[v * 32 + k] * Wih_r[j * 32 + k];
  }
  gb[j] = gr;
  __syncthreads();
  if (j < 128) {
    float c = sig_ref(gb[j]) * tanh_ref(gb[256 + j]);
    hb[j] = sig_ref(gb[384 + j]) * tanh_ref(c);
  }
  __syncthreads();

  // Pg[v][h][g] = bf16(scale(g) * P[v][g*128+h])
  { int h = j >> 2, g = j & 3;
    float sc = (g == 2) ? TWO_LOG2E_F : -LOG2E_F;
    Pg[((size_t)v * 128 + h) * 4 + g] = f2bf(ps[g * 128 + h] * sc); }

  if (j < 32) {
    float s2 = b1[j];
    for (int m = 0; m < 128; ++m) s2 += hb[m] * W1[(128 + m) * 32 + j];
    FB[v * 32 + j] = s2;
  }

  if (v == 0) {
    // BfragW flat = ((nt*4+ks)*64 + lane)*8 + e ; val = scale * Whh_f[n][k]
    for (int f = j; f < 65536; f += 512) {
      int e = f & 7, l = (f >> 3) & 63, ks = (f >> 9) & 3, nt = f >> 11;
      int n = nt * 16 + (l & 15);
      int k = ks * 32 + (l >> 4) * 8 + e;
      float sc = ((nt >> 3) == 2) ? TWO_LOG2E_F : -LOG2E_F;
      BfragW[f] = f2bf(Whh_f[(size_t)n * 128 + k] * sc);
    }
  }
  if (v == 1) {
    // Bfrag1 flat = ((n2*4+ks)*64 + lane)*8 + e ; B[k][q] = W1[k][q] (k<128)
    for (int f = j; f < 4096; f += 512) {
      int e = f & 7, l = (f >> 3) & 63, ks = (f >> 9) & 3, n2 = f >> 11;
      int q = n2 * 16 + (l & 15);
      int k = ks * 32 + (l >> 4) * 8 + e;
      Bfrag1[f] = f2bf(W1[(size_t)k * 32 + q]);
    }
  }
}

// ---------------- MFMA LSTM: 64 edges/block, 8 waves, 1 barrier/step --------
// mfma(A=W-frag, B=H-frag) -> D: col=lane&15=edge(sub), row=(lane>>4)*4+r=hcol.
// Wave wv2 owns hcols [wv2*16,+16) x 4 gates for all 4 edge sub-tiles.
__global__ __launch_bounds__(512, 4) void lstm_mfma_kernel(
    const int*   __restrict__ tokens,   // [E][16]
    const unsigned short* __restrict__ Pg,      // [64][128][4] bf16 (scaled)
    const unsigned short* __restrict__ BfragW,  // [32][4][64][8] bf16 (scaled)
    const unsigned short* __restrict__ Bfrag1,  // [2][4][64][8] bf16
    const float* __restrict__ FB,       // [64][32]
    const float* __restrict__ W2,       // [32]
    const float* __restrict__ b2,
    float* __restrict__ ea, int E, int nTiles)
{
  __shared__ unsigned short Hs[2][EDGES_T * HS_STRIDE];  // 34,816 B
  __shared__ int toks[16][EDGES_T];                      //  4,096 B

  int tid  = threadIdx.x;
  int lane = tid & 63;
  int wv2  = tid >> 6;                  // 0..7
  int l15  = lane & 15;
  int lg   = lane >> 4;                 // 0..3
  int hbase = wv2 * 16 + lg * 4;        // this lane's 4 hcols

  // persistent A-frags (W): BW[gate][ks]
  bf16x8 BW[4][4];
  #pragma unroll
  for (int gate = 0; gate < 4; ++gate)
    #pragma unroll
    for (int ks = 0; ks < 4; ++ks)
      BW[gate][ks] = *(const bf16x8*)(BfragW +
          ((size_t)((gate * 8 + wv2) * 4 + ks) * 64 + lane) * 8);
  float4 w2lo = *(const float4*)(W2 + lg * 4);
  float4 w2hi = *(const float4*)(W2 + 16 + lg * 4);
  float b2v = b2[0];

  for (int tile = blockIdx.x; tile < nTiles; tile += gridDim.x) {
    int e0 = tile * EDGES_T;
    for (int i = tid; i < 16 * EDGES_T; i += 512) {   // stage tokens [t][m]
      int m = i >> 4, t = i & 15;
      int ee = e0 + m; if (ee >= E) ee = E - 1;
      toks[t][m] = tokens[(size_t)ee * 16 + t];
    }
    __syncthreads();

    f32x4 cst[4];   // [es][r], statically indexed (es fully unrolled)
    // ---- step 0: gates = P only (h0=c0=0, f-term vanishes)
    #pragma unroll
    for (int es = 0; es < 4; ++es) {
      int eL = es * 16 + l15;
      int v0 = toks[0][eL];
      const uint4* pp = (const uint4*)(Pg + ((size_t)v0 * 128 + hbase) * 4);
      uint4 pa = pp[0], pb = pp[1];
      float pi[4] = {bflo2f(pa.x), bflo2f(pa.z), bflo2f(pb.x), bflo2f(pb.z)};
      float pg[4] = {bflo2f(pa.y), bflo2f(pa.w), bflo2f(pb.y), bflo2f(pb.w)};
      float po[4] = {bfhi2f(pa.y), bfhi2f(pa.w), bfhi2f(pb.y), bfhi2f(pb.w)};
      float h[4];
      #pragma unroll
      for (int r = 0; r < 4; ++r) {
        float A = fast_exp2(pi[r]);
        float B = fast_exp2(pg[r]);
        float O = fast_exp2(po[r]);
        float cn = pair_sig_tanh(A, B);     // i*g
        cst[es][r] = cn;
        float C = fast_exp2(TWO_LOG2E_F * cn);
        h[r] = pair_sig_tanh(O, C);         // o*tanh(c)
      }
      uint2 hp = make_uint2(cvt_pk_bf16(h[0], h[1]), cvt_pk_bf16(h[2], h[3]));
      *(uint2*)(&Hs[0][eL * HS_STRIDE + hbase]) = hp;
    }
    __syncthreads();

    int cur = 0;
    #pragma unroll 1
    for (int t = 1; t < 16; ++t) {
      #pragma unroll
      for (int es = 0; es < 4; ++es) {
        int eL = es * 16 + l15;
        int vt = toks[t][eL];
        const uint4* pp = (const uint4*)(Pg + ((size_t)vt * 128 + hbase) * 4);
        uint4 pa = pp[0], pb = pp[1];
        f32x4 acc[4];
        acc[0] = (f32x4){bflo2f(pa.x), bflo2f(pa.z), bflo2f(pb.x), bflo2f(pb.z)}; // i
        acc[1] = (f32x4){bfhi2f(pa.x), bfhi2f(pa.z), bfhi2f(pb.x), bfhi2f(pb.z)}; // f
        acc[2] = (f32x4){bflo2f(pa.y), bflo2f(pa.w), bflo2f(pb.y), bflo2f(pb.w)}; // g
        acc[3] = (f32x4){bfhi2f(pa.y), bfhi2f(pa.w), bfhi2f(pb.y), bfhi2f(pb.w)}; // o

        #pragma unroll
        for (int ks = 0; ks < 4; ++ks) {
          bf16x8 Hf = *(const bf16x8*)(&Hs[cur][eL * HS_STRIDE + ks * 32 + lg * 8]);
          #pragma unroll
          for (int gate = 0; gate < 4; ++gate)
            acc[gate] = __builtin_amdgcn_mfma_f32_16x16x32_bf16(
                BW[gate][ks], Hf, acc[gate], 0, 0, 0);
        }

        float h[4];
        #pragma unroll
        for (int r = 0; r < 4; ++r) {
          float A = fast_exp2(acc[0][r]);
          float F = fast_exp2(acc[1][r]);
          float B = fast_exp2(acc[2][r]);
          float O = fast_exp2(acc[3][r]);
          float ig = pair_sig_tanh(A, B);
          float f  = fast_rcp(1.0f + F);
          float cn = fmaf(f, cst[es][r], ig);
          cst[es][r] = cn;
          float C = fast_exp2(TWO_LOG2E_F * cn);
          h[r] = pair_sig_tanh(O, C);
        }
        uint2 hp = make_uint2(cvt_pk_bf16(h[0], h[1]), cvt_pk_bf16(h[2], h[3]));
        *(uint2*)(&Hs[cur ^ 1][eL * HS_STRIDE + hbase]) = hp;
      }
      cur ^= 1;
      __syncthreads();
    }

    // ---- tail: waves 0..3 each handle edge sub-tile es=wv2
    if (wv2 < 4) {
      int eL = wv2 * 16 + l15;
      bf16x8 Hf[4];
      #pragma unroll
      for (int ks = 0; ks < 4; ++ks)
        Hf[ks] = *(const bf16x8*)(&Hs[cur][eL * HS_STRIDE + ks * 32 + lg * 8]);
      f32x4 a2[2];
      a2[0] = (f32x4){0.f, 0.f, 0.f, 0.f};
      a2[1] = (f32x4){0.f, 0.f, 0.f, 0.f};
      #pragma unroll
      for (int ks = 0; ks < 4; ++ks)
        #pragma unroll
        for (int n2 = 0; n2 < 2; ++n2)
          a2[n2] = __builtin_amdgcn_mfma_f32_16x16x32_bf16(
              *(const bf16x8*)(Bfrag1 + ((size_t)(n2 * 4 + ks) * 64 + lane) * 8),
              Hf[ks], a2[n2], 0, 0, 0);
      int v15 = toks[15][eL];
      float4 fb0 = *(const float4*)(FB + v15 * 32 + lg * 4);
      float4 fb1 = *(const float4*)(FB + v15 * 32 + 16 + lg * 4);
      float pr = fmaxf(a2[0][0] + fb0.x, 0.f) * w2lo.x
               + fmaxf(a2[0][1] + fb0.y, 0.f) * w2lo.y
               + fmaxf(a2[0][2] + fb0.z, 0.f) * w2lo.z
               + fmaxf(a2[0][3] + fb0.w, 0.f) * w2lo.w
               + fmaxf(a2[1][0] + fb1.x, 0.f) * w2hi.x
               + fmaxf(a2[1][1] + fb1.y, 0.f) * w2hi.y
               + fmaxf(a2[1][2] + fb1.z, 0.f) * w2hi.z
               + fmaxf(a2[1][3] + fb1.w, 0.f) * w2hi.w;
      pr += __shfl_xor(pr, 16);
      pr += __shfl_xor(pr, 32);
      int eidx = e0 + eL;
      if (lane < 16 && eidx < E) ea[eidx] = fmaxf(pr + b2v, 0.0f);
    }
    __syncthreads();   // before next tile reuses toks/Hs
  }
}

// ---------------- argmax ids + scatter winner (last edge wins) ----------------
__global__ void argmax_winner_kernel(
    const float* __restrict__ x, const int* __restrict__ ei, int E,
    int* __restrict__ srcid, int* __restrict__ tgtid,
    int* __restrict__ win_in, int* __restrict__ win_out)
{
  int e = blockIdx.x * 256 + threadIdx.x;
  if (e >= E) return;
  int s = ei[e];
  int t = ei[E + e];
  const float* xs = x + (size_t)s * D_DIM;
  int sid = 0; float bv = xs[0];
  for (int k = 1; k < SID_N; ++k) { float v = xs[k]; if (v > bv) { bv = v; sid = k; } }
  const float* xt = x + (size_t)t * D_DIM;
  int tix = 0; bv = xt[0];
  for (int k = 1; k < SID_N; ++k) { float v = xt[k]; if (v > bv) { bv = v; tix = k; } }
  srcid[e] = sid;
  tgtid[e] = tix;
  atomicMax(&win_in[(size_t)t * SID_N + sid], e);
  atomicMax(&win_out[(size_t)s * SID_N + tix], e);
}

__global__ void scatter_resolve_kernel(
    const int* __restrict__ ei, const float* __restrict__ ea,
    const int* __restrict__ srcid, const int* __restrict__ tgtid,
    const int* __restrict__ win_in, const int* __restrict__ win_out,
    float* __restrict__ x_mod, int E)
{
  int e = blockIdx.x * 256 + threadIdx.x;
  if (e >= E) return;
  int s = ei[e];
  int t = ei[E + e];
  int sid = srcid[e], tix = tgtid[e];
  if (win_in[(size_t)t * SID_N + sid] == e)
    x_mod[(size_t)t * D_DIM + IN_COL + sid] = ea[e];
  if (win_out[(size_t)s * SID_N + tix] == e)
    x_mod[(size_t)s * D_DIM + OUT_COL + tix] = ea[e];
}

// ---------------- pack Wl||Wr into MFMA fragment order ----------------
__global__ void pack_w_kernel(const float* __restrict__ Wl,
                              const float* __restrict__ Wr,
                              unsigned short* __restrict__ Wfrag)
{
  int f = blockIdx.x * 256 + threadIdx.x;
  if (f >= 48 * 12 * 64 * 8) return;
  int e = f & 7, l = (f >> 3) & 63;
  int rest = f >> 9;
  int ks = rest % 12, nt = rest / 12;
  int nl = nt * 16 + (l & 15);
  int k  = ks * 32 + (l >> 4) * 8 + e;
  float val = 0.0f;
  if (k < D_DIM) {
    if (nl < D_DIM)                      val = Wl[(size_t)k * D_DIM + nl];
    else if (nl >= 384 && nl < 384 + D_DIM) val = Wr[(size_t)k * D_DIM + (nl - 384)];
  }
  Wfrag[f] = f2bf(val);
}

// ---------------- fused bf16 MFMA GEMM: [xl||xr] = xmod @ [Wl||Wr] + bias ----
__global__ __launch_bounds__(256, 2) void gemm_mfma_kernel(
    const float* __restrict__ A,               // xmod [N][373] fp32
    const unsigned short* __restrict__ Wfrag,  // [48][12][64][8] bf16
    const float* __restrict__ bl, const float* __restrict__ br,
    float* __restrict__ xl, float* __restrict__ xr, int N)
{
  __shared__ unsigned short As[64][40];
  int tid  = threadIdx.x;
  int lane = tid & 63;
  int wv   = tid >> 6;
  int l15  = lane & 15, lg = lane >> 4;
  int m0   = blockIdx.x * 64;
  int nt   = blockIdx.y * 4 + wv;

  f32x4 acc[4];
  #pragma unroll
  for (int i = 0; i < 4; ++i) acc[i] = (f32x4){0.f, 0.f, 0.f, 0.f};

  int srow = tid >> 2, seg = tid & 3;
  int gr = m0 + srow; if (gr >= N) gr = N - 1;
  const float* arow = A + (size_t)gr * D_DIM;

  for (int ks = 0; ks < 12; ++ks) {
    int c0 = ks * 32 + seg * 8;
    float v[8];
    #pragma unroll
    for (int j = 0; j < 8; ++j) v[j] = (c0 + j < D_DIM) ? arow[c0 + j] : 0.0f;
    unsigned pk0 = cvt_pk_bf16(v[0], v[1]);
    unsigned pk1 = cvt_pk_bf16(v[2], v[3]);
    unsigned pk2 = cvt_pk_bf16(v[4], v[5]);
    unsigned pk3 = cvt_pk_bf16(v[6], v[7]);
    __syncthreads();
    *(uint4*)(&As[srow][seg * 8]) = make_uint4(pk0, pk1, pk2, pk3);
    __syncthreads();

    bf16x8 Bf = *(const bf16x8*)(Wfrag + ((size_t)(nt * 12 + ks) * 64 + lane) * 8);
    #pragma unroll
    for (int msub = 0; msub < 4; ++msub) {
      bf16x8 Af = *(const bf16x8*)(&As[msub * 16 + l15][lg * 8]);
      acc[msub] = __builtin_amdgcn_mfma_f32_16x16x32_bf16(Af, Bf, acc[msub], 0, 0, 0);
    }
  }

  int nl = nt * 16 + l15;
  float* dst = nullptr; int col = 0; const float* bias_ = nullptr;
  if (nl < D_DIM)                         { dst = xl; col = nl;       bias_ = bl; }
  else if (nl >= 384 && nl < 384 + D_DIM) { dst = xr; col = nl - 384; bias_ = br; }
  if (dst) {
    float bv = bias_[col];
    #pragma unroll
    for (int msub = 0; msub < 4; ++msub) {
      #pragma unroll
      for (int r = 0; r < 4; ++r) {
        int m = m0 + msub * 16 + lg * 4 + r;
        if (m < N) dst[(size_t)m * D_DIM + col] = acc[msub][r] + bv;
      }
    }
  }
}

// ---------------- GAT: attention logits (no atomics) ----------------
__global__ __launch_bounds__(256) void edge_e_kernel(
    const float* __restrict__ xl, const float* __restrict__ xr,
    const float* __restrict__ att, const int* __restrict__ ei,
    float* __restrict__ e_buf, int E)
{
  int widx = (blockIdx.x * 256 + threadIdx.x) >> 6;
  int lane = threadIdx.x & 63;
  if (widx >= E) return;
  int s = ei[widx], t = ei[E + widx];
  const float* pl = xl + (size_t)s * D_DIM;
  const float* pr = xr + (size_t)t * D_DIM;
  float acc = 0.0f;
  for (int d = lane; d < D_DIM; d += 64) {
    float m = pl[d] + pr[d];
    m = (m > 0.0f) ? m : 0.2f * m;
    acc += m * att[d];
  }
  #pragma unroll
  for (int o = 32; o > 0; o >>= 1) acc += __shfl_down(acc, o);
  if (lane == 0) e_buf[widx] = acc;
}

// ---------------- CSR build: histogram / scan / placement ----------------
__global__ void hist_kernel(const int* __restrict__ ei, unsigned* __restrict__ deg,
                            int E) {
  int e = blockIdx.x * 256 + threadIdx.x;
  if (e >= E) return;
  atomicAdd(&deg[ei[E + e]], 1u);
}

__global__ void scan1_kernel(const unsigned* __restrict__ deg,
                             unsigned* __restrict__ excl,
                             unsigned* __restrict__ bsum, int n) {
  __shared__ unsigned s[256];
  int t = threadIdx.x;
  int i = blockIdx.x * 256 + t;
  unsigned v = (i < n) ? deg[i] : 0u;
  s[t] = v; __syncthreads();
  #pragma unroll
  for (int o = 1; o < 256; o <<= 1) {
    unsigned u = (t >= o) ? s[t - o] : 0u;
    __syncthreads();
    s[t] += u;
    __syncthreads();
  }
  if (i < n) excl[i] = s[t] - v;
  if (t == 255) bsum[blockIdx.x] = s[255];
}

__global__ void scan2_kernel(unsigned* __restrict__ bsum, int nb) {
  __shared__ unsigned s[256];
  int t = threadIdx.x;
  unsigned v = (t < nb) ? bsum[t] : 0u;
  s[t] = v; __syncthreads();
  #pragma unroll
  for (int o = 1; o < 256; o <<= 1) {
    unsigned u = (t >= o) ? s[t - o] : 0u;
    __syncthreads();
    s[t] += u;
    __syncthreads();
  }
  if (t < nb) bsum[t] = s[t] - v;   // exclusive
}

__global__ void scan3_kernel(unsigned* __restrict__ excl,
                             const unsigned* __restrict__ bsum, int n) {
  int i = blockIdx.x * 256 + threadIdx.x;
  if (i < n) excl[i] += bsum[i >> 8];
}

__global__ void place_kernel(const int* __restrict__ ei,
                             unsigned* __restrict__ offs,
                             int* __restrict__ csr_eid, int E) {
  int e = blockIdx.x * 256 + threadIdx.x;
  if (e >= E) return;
  unsigned j = atomicAdd(&offs[ei[E + e]], 1u);
  csr_eid[j] = e;
}

// ---------------- fused per-node: softmax + aggregate + finalize ----------
__global__ __launch_bounds__(256) void node_gat_kernel(
    const int* __restrict__ ei, const int* __restrict__ csr_eid,
    const unsigned* __restrict__ offs, const unsigned* __restrict__ deg,
    float* __restrict__ ebuf, const float* __restrict__ xl,
    const float* __restrict__ xmod, const float* __restrict__ bias,
    float* __restrict__ out, int N, int E, int goff)
{
  int n = (blockIdx.x * 256 + threadIdx.x) >> 6;
  int lane = threadIdx.x & 63;
  if (n >= N) return;
  unsigned end = offs[n], d = deg[n], start = end - d;

  float mx = -3.4e38f;
  for (unsigned j = start; j < end; ++j)
    mx = fmaxf(mx, ebuf[csr_eid[j]]);
  float den = 0.0f;
  for (unsigned j = start; j < end; ++j) {
    int eid = csr_eid[j];
    float ex = __expf(ebuf[eid] - mx);
    ebuf[eid] = ex;               // reuse in agg pass (exclusive to this wave)
    den += ex;
  }
  float inv = 1.0f / (den + 1e-16f);

  float o0 = 0, o1 = 0, o2 = 0, o3 = 0, o4 = 0, o5 = 0;
  for (unsigned j = start; j < end; ++j) {
    int eid = csr_eid[j];
    float w = ebuf[eid] * inv;
    const float* row = xl + (size_t)ei[eid] * D_DIM;
    o0 = fmaf(w, row[lane], o0);
    o1 = fmaf(w, row[64 + lane], o1);
    o2 = fmaf(w, row[128 + lane], o2);
    o3 = fmaf(w, row[192 + lane], o3);
    o4 = fmaf(w, row[256 + lane], o4);
    if (lane < 53) o5 = fmaf(w, row[320 + lane], o5);
  }

  const float* xm = xmod + (size_t)n * D_DIM;
  float* op = out + (size_t)n * (2 * D_DIM) + goff;
  op[lane]       = fmaxf(o0 + bias[lane]       + xm[lane],       0.0f);
  op[64 + lane]  = fmaxf(o1 + bias[64 + lane]  + xm[64 + lane],  0.0f);
  op[128 + lane] = fmaxf(o2 + bias[128 + lane] + xm[128 + lane], 0.0f);
  op[192 + lane] = fmaxf(o3 + bias[192 + lane] + xm[192 + lane], 0.0f);
  op[256 + lane] = fmaxf(o4 + bias[256 + lane] + xm[256 + lane], 0.0f);
  if (lane < 53)
    op[320 + lane] = fmaxf(o5 + bias[320 + lane] + xm[320 + lane], 0.0f);
}

// ---------------------------------------------------------------------------
extern "C" void kernel_launch(void* const* d_in, const int* in_sizes, int n_in,
                              void* d_out, int out_size, void* d_ws, size_t ws_size,
                              hipStream_t stream)
{
  const float* fx     = (const float*)d_in[0];
  const float* bx     = (const float*)d_in[1];
  const int*   fei    = (const int*)d_in[2];
  const int*   bei    = (const int*)d_in[3];
  const int*   ftk    = (const int*)d_in[4];
  const int*   btk    = (const int*)d_in[5];
  const float* embed  = (const float*)d_in[6];
  const float* Wih_f  = (const float*)d_in[7];
  const float* Whh_f  = (const float*)d_in[8];
  const float* bih_f  = (const float*)d_in[9];
  const float* bhh_f  = (const float*)d_in[10];
  const float* Wih_r  = (const float*)d_in[11];
  // d_in[12] = Whh_r : unused (reverse cell consumes zero state)
  const float* bih_r  = (const float*)d_in[13];
  const float* bhh_r  = (const float*)d_in[14];
  const float* W1     = (const float*)d_in[15];
  const float* b1     = (const float*)d_in[16];
  const float* W2     = (const float*)d_in[17];
  const float* b2     = (const float*)d_in[18];

  const float* Wl_g[2]   = {(const float*)d_in[19], (const float*)d_in[25]};
  const float* bl_g[2]   = {(const float*)d_in[20], (const float*)d_in[26]};
  const float* Wr_g[2]   = {(const float*)d_in[21], (const float*)d_in[27]};
  const float* br_g[2]   = {(const float*)d_in[22], (const float*)d_in[28]};
  const float* att_g[2]  = {(const float*)d_in[23], (const float*)d_in[29]};
  const float* bias_g[2] = {(const float*)d_in[24], (const float*)d_in[30]};
  const float* x_g[2]    = {fx, bx};
  const int*   ei_g[2]   = {fei, bei};
  const int*   tk_g[2]   = {ftk, btk};

  const int E = in_sizes[2] / 2;          // 400000
  const int N = in_sizes[0] / D_DIM;      // 50000

  // ---- workspace layout (byte-based, 256B aligned chunks) ----
  char* wsb = (char*)d_ws;
  size_t off = 0;
  auto alloc = [&](size_t bytes) -> void* {
    void* p = wsb + off; off += (bytes + 255) & ~(size_t)255; return p;
  };
  unsigned short* Pg     = (unsigned short*)alloc((size_t)64 * 128 * 4 * 2);
  unsigned short* BfragW = (unsigned short*)alloc((size_t)65536 * 2);
  unsigned short* Bfrag1 = (unsigned short*)alloc((size_t)4096 * 2);
  unsigned short* Wfrag2 = (unsigned short*)alloc((size_t)2 * 294912 * 2);
  float* FB    = (float*)alloc((size_t)64 * 32 * 4);
  float* ea    = (float*)alloc((size_t)E * 4);
  float* ebuf  = (float*)alloc((size_t)E * 4);
  int*   srcid = (int*)alloc((size_t)E * 4);
  int*   tgtid = (int*)alloc((size_t)E * 4);
  int*   csr_eid = (int*)alloc((size_t)E * 4);
  unsigned* deg  = (unsigned*)alloc((size_t)N * 4);
  unsigned* offs = (unsigned*)alloc((size_t)N * 4);
  unsigned* bsum = (unsigned*)alloc((size_t)256 * 4);
  int* win_in  = (int*)alloc((size_t)N * SID_N * 4);
  int* win_out = (int*)alloc((size_t)N * SID_N * 4);
  float* xmod  = (float*)alloc((size_t)N * D_DIM * 4);
  float* xl    = (float*)alloc((size_t)N * D_DIM * 4);
  float* xr    = (float*)alloc((size_t)N * D_DIM * 4);
  (void)ws_size; (void)n_in; (void)out_size;

  const size_t win_u32 = (size_t)((char*)win_out - (char*)win_in) / 4
                         + (size_t)N * SID_N;

  float* out = (float*)d_out;

  precompute_kernel<<<64, 512, 0, stream>>>(
      embed, Wih_f, Whh_f, bih_f, bhh_f, Wih_r, bih_r, bhh_r, W1, b1,
      Pg, BfragW, Bfrag1, FB);
  pack_w_kernel<<<(294912 + 255) / 256, 256, 0, stream>>>(
      Wl_g[0], Wr_g[0], Wfrag2);
  pack_w_kernel<<<(294912 + 255) / 256, 256, 0, stream>>>(
      Wl_g[1], Wr_g[1], Wfrag2 + 294912);

  const int nTiles  = (E + EDGES_T - 1) / EDGES_T;   // 6250
  const int gridL   = nTiles < 2048 ? nTiles : 2048;
  const int gridE   = (E + 255) / 256;
  const int gridEW  = (E + 3) / 4;
  const int nScanB  = (N + 255) / 256;
  const int gridNd  = (N * 64 + 255) / 256;
  dim3 gridG((N + 63) / 64, 12);

  for (int g = 0; g < 2; ++g) {
    const float* x  = x_g[g];
    const int*   ei = ei_g[g];

    // (1) edge scalar via MFMA LSTM
    lstm_mfma_kernel<<<gridL, 512, 0, stream>>>(tk_g[g], Pg, BfragW, Bfrag1,
                                                FB, W2, b2, ea, E, nTiles);

    // (2) x_mod = copy(x), then last-edge-wins scatter writes
    hipMemcpyAsync(xmod, x, (size_t)N * D_DIM * sizeof(float),
                   hipMemcpyDeviceToDevice, stream);
    fill_u32_kernel<<<2048, 256, 0, stream>>>((unsigned*)win_in, 0xFFFFFFFFu,
                                              win_u32);
    argmax_winner_kernel<<<gridE, 256, 0, stream>>>(x, ei, E, srcid, tgtid,
                                                    win_in, win_out);
    scatter_resolve_kernel<<<gridE, 256, 0, stream>>>(ei, ea, srcid, tgtid,
                                                      win_in, win_out, xmod, E);

    // (3) [xl||xr] = xmod @ [Wl||Wr] + bias  (bf16 MFMA)
    gemm_mfma_kernel<<<gridG, 256, 0, stream>>>(xmod, Wfrag2 + (size_t)g * 294912,
                                                bl_g[g], br_g[g], xl, xr, N);

    // (4) CSR by dst
    fill_u32_kernel<<<512, 256, 0, stream>>>(deg, 0u, (size_t)N);
    hist_kernel<<<gridE, 256, 0, stream>>>(ei, deg, E);
    scan1_kernel<<<nScanB, 256, 0, stream>>>(deg, offs, bsum, N);
    scan2_kernel<<<1, 256, 0, stream>>>(bsum, nScanB);
    scan3_kernel<<<nScanB, 256, 0, stream>>>(offs, bsum, N);
    place_kernel<<<gridE, 256, 0, stream>>>(ei, offs, csr_eid, E);

    // (5) attention logits, then fused softmax+aggregate+finalize
    edge_e_kernel<<<gridEW, 256, 0, stream>>>(xl, xr, att_g[g], ei, ebuf, E);
    node_gat_kernel<<<gridNd, 256, 0, stream>>>(ei, csr_eid, offs, deg, ebuf,
                                                xl, xmod, bias_g[g], out,
                                                N, E, g * D_DIM);
  }
}